// Round 10
// baseline (274.037 us; speedup 1.0000x reference)
//
#include <hip/hip_runtime.h>
#include <hip/hip_bf16.h>

typedef __attribute__((ext_vector_type(8))) short short8;
typedef __attribute__((ext_vector_type(4))) float f32x4;
typedef __attribute__((ext_vector_type(4))) int int4v;
typedef __attribute__((ext_vector_type(8))) char char8v;
typedef __attribute__((ext_vector_type(4), aligned(4))) unsigned int uint4a;

static constexpr int B = 64, N = 198, C = 768, H = 12, D = 64;
static constexpr int M = B * N;          // 12672 = 99*128
static constexpr int BH = B * H;         // 768
static constexpr int NPAD = 208;         // 13*16
static constexpr int ALD = 216;          // P-stripe LDS leading dim (shorts)
static constexpr int O3C = 3 * C;        // 2304 = 18*128
static constexpr int TLD = 136;          // epilogue tile stride (ushorts)
static constexpr int NXB = 99;           // M/128
static constexpr int NXBP = 104;         // padded to 13*8 for XCD affinity

// ---- workspace layout (bytes) ----
static constexpr size_t OFF_MEANS = 0;
static constexpr size_t OFF_TAB   = 256;
static constexpr size_t OFF_PARTA = 2048;
static constexpr size_t OFF_PARTP = 4096;
static constexpr size_t OFF_XS    = 8192;
static constexpr size_t SZ_XS     = (size_t)M * C;           // sign(x) i8
static constexpr size_t OFF_WQS   = OFF_XS + SZ_XS;
static constexpr size_t SZ_WQS    = (size_t)O3C * C;         // sign(qkv_w) i8
static constexpr size_t OFF_WPS   = OFF_WQS + SZ_WQS;
static constexpr size_t SZ_WPS    = (size_t)C * C;           // sign(proj_w) i8
static constexpr size_t OFF_Q     = OFF_WPS + SZ_WPS;
static constexpr size_t SZ_QK     = (size_t)BH * N * D * 2;  // bf16
static constexpr size_t OFF_K     = OFF_Q + SZ_QK;
static constexpr size_t OFF_VT    = OFF_K + SZ_QK;
static constexpr size_t SZ_VT     = (size_t)BH * D * NPAD * 2; // bf16
static constexpr size_t OFF_OS    = OFF_VT + SZ_VT;          // sign(attn_out) i8

static __device__ inline unsigned short f2bf(float x) {
  union { __hip_bfloat16 h; unsigned short u; } cv;
  cv.h = __float2bfloat16(x);
  return cv.u;
}

// ---------- mean(|W|) reduction: deterministic 2-phase ----------
__global__ void reduce_abs_kernel(const float* __restrict__ w, int n, double* __restrict__ part) {
  __shared__ double sm[256];
  double s = 0.0;
  for (int i = blockIdx.x * 256 + threadIdx.x; i < n; i += 256 * gridDim.x)
    s += (double)fabsf(w[i]);
  sm[threadIdx.x] = s;
  __syncthreads();
  for (int off = 128; off > 0; off >>= 1) {
    if (threadIdx.x < (unsigned)off) sm[threadIdx.x] += sm[threadIdx.x + off];
    __syncthreads();
  }
  if (threadIdx.x == 0) part[blockIdx.x] = sm[0];
}

__global__ void finalize_kernel(const double* __restrict__ pA, const double* __restrict__ pP,
                                double* __restrict__ means, double* __restrict__ tab,
                                const float* cq, const float* ck) {
  __shared__ double sm[256];
  int t = threadIdx.x;
  sm[t] = pA[t];
  __syncthreads();
  for (int off = 128; off > 0; off >>= 1) { if (t < off) sm[t] += sm[t + off]; __syncthreads(); }
  if (t == 0) means[0] = sm[0] / (double)((size_t)O3C * C);
  __syncthreads();
  sm[t] = pP[t];
  __syncthreads();
  for (int off = 128; off > 0; off >>= 1) { if (t < off) sm[t] += sm[t + off]; __syncthreads(); }
  if (t == 0) means[1] = sm[0] / (double)((size_t)C * C);
  double delta = (double)cq[0] * (double)ck[0] * 0.125;
  if (t < 129) tab[t] = exp((double)(t - 128) * delta);
}

// ---------- sign (binarize) to i8 {-1,0,1}, 8/thread ----------
__global__ void sign8_kernel(const float* __restrict__ x, signed char* __restrict__ out,
                             int n8, const float* alpha) {
  float a = alpha ? alpha[0] : 1.0f;
  signed char pos = (a > 0.0f) ? 1 : ((a < 0.0f) ? -1 : 0);
  signed char neg = (signed char)(-pos);
  int stride = 256 * gridDim.x;
  for (int i = blockIdx.x * 256 + threadIdx.x; i < n8; i += stride) {
    const float4* xp = (const float4*)(x + (size_t)i * 8);
    float4 u = xp[0], v = xp[1];
    float vals[8] = {u.x, u.y, u.z, u.w, v.x, v.y, v.z, v.w};
    char8v s;
#pragma unroll
    for (int j = 0; j < 8; ++j)
      s[j] = vals[j] > 0.0f ? pos : (vals[j] < 0.0f ? neg : (signed char)0);
    *(char8v*)(out + (size_t)i * 8) = s;
  }
}

// XCD-affinity decode: all y-blocks of an x-tile share lin%8 -> same XCD.
static __device__ inline bool xcd_decode(int lin, int nyb, int& x, int& y) {
  int k = lin & 7;
  int q = lin >> 3;
  int xi = q / nyb;
  y = q - xi * nyb;
  x = xi * 8 + k;
  return x < NXB;
}

// ---------- i8 MFMA GEMM core, barrier-free: fragments loaded global->reg ----------
// Operands are L2-resident (XCD-affine grid); 16B/lane loads, 4 lanes per 64B
// line. Fully unrolled: compiler interleaves the 96 loads with 192 MFMAs
// under counted vmcnt -- no __syncthreads, no LDS staging.
static __device__ inline void gemm_bt_core_i8(const signed char* __restrict__ A,
                                              const signed char* __restrict__ Bmat,
                                              int i0, int o0,
                                              int4v acc[4][4]) {
  int tid = threadIdx.x;
  int lane = tid & 63, w = tid >> 6, wr = w >> 1, wc = w & 1;
  int q16 = lane & 15, hi = lane >> 4;
  const signed char* Ab = A + (size_t)(i0 + wr * 64 + q16) * C;
  const signed char* Bb = Bmat + (size_t)(o0 + wc * 64 + q16) * C;
#pragma unroll
  for (int k0 = 0; k0 < C; k0 += 128) {
#pragma unroll
    for (int kk = 0; kk < 2; ++kk) {
      int col = k0 + (kk * 4 + hi) * 16;
      int4v af[4], bf[4];
#pragma unroll
      for (int m = 0; m < 4; ++m)
        af[m] = *(const int4v*)&Ab[(size_t)(m * 16) * C + col];
#pragma unroll
      for (int n2 = 0; n2 < 4; ++n2)
        bf[n2] = *(const int4v*)&Bb[(size_t)(n2 * 16) * C + col];
#pragma unroll
      for (int m = 0; m < 4; ++m)
#pragma unroll
        for (int n2 = 0; n2 < 4; ++n2)
          acc[m][n2] = __builtin_amdgcn_mfma_i32_16x16x64_i8(af[m], bf[n2], acc[m][n2], 0, 0, 0);
    }
  }
}

// ---------- GEMM1: qkv = sign(x) @ sign(Wqkv)^T ----------
__global__ __launch_bounds__(256) void gemm1_kernel(
    const signed char* __restrict__ Xs, const signed char* __restrict__ Wqs,
    const double* __restrict__ means,
    const float* cin, const float* cq, const float* ck,
    const float* cv1, const float* cv2, const float* cv3,
    const float* __restrict__ movq, const float* __restrict__ movk, const float* __restrict__ movv,
    unsigned short* __restrict__ Qs, unsigned short* __restrict__ Ks, unsigned short* __restrict__ Vt) {
  int bx, by;
  if (!xcd_decode(blockIdx.x, O3C / 128, bx, by)) return;
  __shared__ __align__(16) unsigned short tile[128 * TLD];   // 34816 B
  int4v acc[4][4] = {};
  int i0 = bx * 128, o0 = by * 128;
  gemm_bt_core_i8(Xs, Wqs, i0, o0, acc);
  int tid = threadIdx.x;
  int lane = tid & 63, w = tid >> 6, wr = w >> 1, wc = w & 1;
  double cw_ = (double)cin[0] * means[0];
  float dq = cq[0], dk = ck[0];
  float sq = dq > 0.0f ? 1.0f : (dq < 0.0f ? -1.0f : 0.0f);
  float sk = dk > 0.0f ? 1.0f : (dk < 0.0f ? -1.0f : 0.0f);
  double aa1 = fabs((double)cv1[0]), aa2 = fabs((double)cv2[0]), aa3 = fabs((double)cv3[0]);
  int t = o0 / C;
  int rem0 = o0 - t * C;
  float sgn = t == 0 ? sq : sk;
  const float* mov = t == 0 ? movq : (t == 1 ? movk : movv);
#pragma unroll
  for (int m = 0; m < 4; ++m)
#pragma unroll
    for (int n2 = 0; n2 < 4; ++n2)
#pragma unroll
      for (int r = 0; r < 4; ++r) {
        int rowL = wr * 64 + m * 16 + (lane >> 4) * 4 + r;
        int colL = wc * 64 + n2 * 16 + (lane & 15);
        int rem = rem0 + colL;
        int h = rem >> 6, d = rem & 63;
        double g = (double)acc[m][n2][r] * cw_;
        if (t < 2) {
          double v = g + (double)mov[h * D + d];
          float s = v > 0.0 ? sgn : (v < 0.0 ? -sgn : 0.0f);
          tile[rowL * TLD + colL] = f2bf(s);
        } else {
          double rr = g + (double)mov[h * D + d];
          double b1 = rr > 0.0 ? aa1 : (rr < 0.0 ? -aa1 : 0.0);
          rr -= b1;
          double b2 = rr > 0.0 ? aa2 : (rr < 0.0 ? -aa2 : 0.0);
          rr -= b2;
          double b3 = rr > 0.0 ? aa3 : (rr < 0.0 ? -aa3 : 0.0);
          tile[colL * TLD + rowL] = f2bf((float)(b1 + b2 + b3));  // transposed
        }
      }
  __syncthreads();
  if (t < 2) {
    unsigned short* dst = t == 0 ? Qs : Ks;
#pragma unroll
    for (int it = 0; it < 8; ++it) {
      int c = tid + it * 256;
      int rowL = c >> 4, cch = c & 15;
      int gr = i0 + rowL;
      int b = gr / N, nn = gr - b * N;
      int rem = rem0 + cch * 8;
      int h = rem >> 6, d = rem & 63;
      uint4a vdata = *(const uint4a*)&tile[rowL * TLD + cch * 8];
      *(uint4a*)&dst[((size_t)(b * H + h) * N + nn) * D + d] = vdata;
    }
  } else {
#pragma unroll
    for (int it = 0; it < 8; ++it) {
      int c = tid + it * 256;
      int colL = c >> 4, tch = c & 15;
      int rem = rem0 + colL;
      int h = rem >> 6, d = rem & 63;
      int gr0 = i0 + tch * 8;
      int b0 = gr0 / N, nn0 = gr0 - b0 * N;
      uint4a vdata = *(const uint4a*)&tile[colL * TLD + tch * 8];
      if (nn0 + 8 <= N) {
        *(uint4a*)&Vt[((size_t)(b0 * H + h) * D + d) * NPAD + nn0] = vdata;
      } else {
        const unsigned short* pv = (const unsigned short*)&vdata;
#pragma unroll
        for (int j = 0; j < 8; ++j) {
          int gr = gr0 + j;
          int b = gr / N, nn = gr - b * N;
          Vt[((size_t)(b * H + h) * D + d) * NPAD + nn] = pv[j];
        }
      }
    }
  }
}

// ---------- fused attention v4: 1 wave per (rt, bh), XCD-aware placement ----------
__global__ __launch_bounds__(64) void attn_kernel(
    const unsigned short* __restrict__ Qs, const unsigned short* __restrict__ Ks,
    const unsigned short* __restrict__ Vt, const double* __restrict__ tab,
    const float* __restrict__ movatt,
    const float* ca1p, const float* ca2p, const float* ca3p, const float* cipp,
    signed char* __restrict__ Os) {
  __shared__ double tabl[132];
  __shared__ unsigned short Al[16 * ALD];
  int i = blockIdx.x;
  int xcd = i & 7;
  int j = i >> 3;
  int rt = j % 13;
  int bh = (j / 13) * 8 + xcd;   // bh % 8 == i % 8
  int b = bh / H, h = bh - b * H;
  int lane = threadIdx.x;
  int g = lane >> 4, q16 = lane & 15;
  for (int ii = lane; ii < 129; ii += 64) tabl[ii] = tab[ii];
  __syncthreads();
  double ca1 = (double)ca1p[0], ca2 = (double)ca2p[0], ca3 = (double)ca3p[0];
  double t1 = 0.5 * ca1, t2 = 0.5 * ca2, t3 = 0.5 * ca3;
  float cip = cipp[0];
  float sgn_cip = cip > 0.0f ? 1.0f : (cip < 0.0f ? -1.0f : 0.0f);

  short8 qf[2];
  int qrow = rt * 16 + q16;
#pragma unroll
  for (int kk = 0; kk < 2; ++kk) {
    short8 z = {};
    qf[kk] = (qrow < N)
        ? *(const short8*)&Qs[((size_t)bh * N + qrow) * D + kk * 32 + g * 8]
        : z;
  }
  f32x4 sacc[13] = {};
#pragma unroll
  for (int kk = 0; kk < 2; ++kk)
#pragma unroll
    for (int ct = 0; ct < 13; ++ct) {
      int krow = ct * 16 + q16;
      short8 z = {};
      short8 kf = (krow < N)
          ? *(const short8*)&Ks[((size_t)bh * N + krow) * D + kk * 32 + g * 8]
          : z;
      sacc[ct] = __builtin_amdgcn_mfma_f32_16x16x32_bf16(qf[kk], kf, sacc[ct], 0, 0, 0);
    }
#pragma unroll
  for (int r = 0; r < 4; ++r) {
    int rowg = rt * 16 + g * 4 + r;
    int rowc = rowg < N ? rowg : N - 1;
    const float* mrow = movatt + ((size_t)h * N + rowc) * N;
    float mx = -3.0e38f;
#pragma unroll
    for (int ct = 0; ct < 13; ++ct) {
      int colc = ct * 16 + q16;
      if (colc < N) mx = fmaxf(mx, sacc[ct][r]);
    }
    mx = fmaxf(mx, __shfl_xor(mx, 1));
    mx = fmaxf(mx, __shfl_xor(mx, 2));
    mx = fmaxf(mx, __shfl_xor(mx, 4));
    mx = fmaxf(mx, __shfl_xor(mx, 8));
    double ev[13];
    double ssum = 0.0;
#pragma unroll
    for (int ct = 0; ct < 13; ++ct) {
      int colc = ct * 16 + q16;
      int idx = (int)(sacc[ct][r] - mx) + 128;
      double e = (colc < N) ? tabl[idx] : 0.0;
      ev[ct] = e;
      ssum += e;
    }
    ssum += __shfl_xor(ssum, 1);
    ssum += __shfl_xor(ssum, 2);
    ssum += __shfl_xor(ssum, 4);
    ssum += __shfl_xor(ssum, 8);
    double rec = 1.0 / ssum;
#pragma unroll
    for (int ct = 0; ct < 13; ++ct) {
      int colc = ct * 16 + q16;
      int colb = colc < N ? colc : N - 1;
      double at = ev[ct] * rec + (double)mrow[colb];
      double b1 = at > t1 ? ca1 : 0.0;
      double rr = at - b1;
      double b2 = rr > t2 ? ca2 : 0.0;
      rr -= b2;
      double b3 = rr > t3 ? ca3 : 0.0;
      float av = (colc < N) ? (float)(b1 + b2 + b3) : 0.0f;
      Al[(g * 4 + r) * ALD + colc] = f2bf(av);
    }
  }
  __syncthreads();
  f32x4 oacc[4] = {};
#pragma unroll
  for (int kt = 0; kt < 7; ++kt) {
    int kbase = kt * 32 + g * 8;
    short8 z = {};
    short8 af = (kbase < NPAD) ? *(const short8*)&Al[q16 * ALD + kbase] : z;
    int kb2 = kbase < NPAD ? kbase : 0;
#pragma unroll
    for (int dt = 0; dt < 4; ++dt) {
      short8 bv = *(const short8*)&Vt[((size_t)bh * 64 + dt * 16 + q16) * NPAD + kb2];
      oacc[dt] = __builtin_amdgcn_mfma_f32_16x16x32_bf16(af, bv, oacc[dt], 0, 0, 0);
    }
  }
#pragma unroll
  for (int dt = 0; dt < 4; ++dt)
#pragma unroll
    for (int r = 0; r < 4; ++r) {
      int rowg = rt * 16 + g * 4 + r;
      if (rowg < N) {
        int d = dt * 16 + q16;
        float v = oacc[dt][r];
        float s = v > 0.0f ? sgn_cip : (v < 0.0f ? -sgn_cip : 0.0f);
        Os[((size_t)(b * N + rowg)) * C + h * D + d] =
            (signed char)(s > 0.0f ? 1 : (s < 0.0f ? -1 : 0));
      }
    }
}

// ---------- GEMM2: out = (cip*sign) @ sign(Wp)^T * wbar + bias -> f32 ----------
__global__ __launch_bounds__(256) void gemm2_kernel(
    const signed char* __restrict__ Os, const signed char* __restrict__ Wps,
    const double* __restrict__ means, const float* cip, const float* __restrict__ proj_b,
    float* __restrict__ out) {
  int bx, by;
  if (!xcd_decode(blockIdx.x, C / 128, bx, by)) return;
  int4v acc[4][4] = {};
  int i0 = bx * 128, o0 = by * 128;
  gemm_bt_core_i8(Os, Wps, i0, o0, acc);
  int lane = threadIdx.x & 63, w = threadIdx.x >> 6, wr = w >> 1, wc = w & 1;
  double cw_ = (double)cip[0] * means[1];
#pragma unroll
  for (int m = 0; m < 4; ++m)
#pragma unroll
    for (int n2 = 0; n2 < 4; ++n2)
#pragma unroll
      for (int r = 0; r < 4; ++r) {
        int row = i0 + wr * 64 + m * 16 + (lane >> 4) * 4 + r;
        int col = o0 + wc * 64 + n2 * 16 + (lane & 15);
        double v = (double)acc[m][n2][r] * cw_ + (double)proj_b[col];
        out[(size_t)row * C + col] = (float)v;
      }
}

extern "C" void kernel_launch(void* const* d_in, const int* in_sizes, int n_in,
                              void* d_out, int out_size, void* d_ws, size_t ws_size,
                              hipStream_t stream) {
  const float* x      = (const float*)d_in[0];
  const float* qkv_w  = (const float*)d_in[1];
  const float* proj_w = (const float*)d_in[2];
  const float* proj_b = (const float*)d_in[3];
  const float* movq   = (const float*)d_in[4];
  const float* movk   = (const float*)d_in[5];
  const float* movv   = (const float*)d_in[6];
  const float* movatt = (const float*)d_in[7];
  const float* c_inq  = (const float*)d_in[8];
  const float* c_q    = (const float*)d_in[9];
  const float* c_k    = (const float*)d_in[10];
  const float* c_v1   = (const float*)d_in[11];
  const float* c_v2   = (const float*)d_in[12];
  const float* c_v3   = (const float*)d_in[13];
  const float* c_a1   = (const float*)d_in[14];
  const float* c_a2   = (const float*)d_in[15];
  const float* c_a3   = (const float*)d_in[16];
  const float* c_inp  = (const float*)d_in[17];

  char* ws = (char*)d_ws;
  double* means = (double*)(ws + OFF_MEANS);
  double* tab   = (double*)(ws + OFF_TAB);
  double* partA = (double*)(ws + OFF_PARTA);
  double* partP = (double*)(ws + OFF_PARTP);
  signed char* Xs  = (signed char*)(ws + OFF_XS);
  signed char* Wqs = (signed char*)(ws + OFF_WQS);
  signed char* Wps = (signed char*)(ws + OFF_WPS);
  unsigned short* Qs  = (unsigned short*)(ws + OFF_Q);
  unsigned short* Ks  = (unsigned short*)(ws + OFF_K);
  unsigned short* Vt  = (unsigned short*)(ws + OFF_VT);
  signed char* Os  = (signed char*)(ws + OFF_OS);

  reduce_abs_kernel<<<256, 256, 0, stream>>>(qkv_w, O3C * C, partA);
  reduce_abs_kernel<<<256, 256, 0, stream>>>(proj_w, C * C, partP);
  finalize_kernel<<<1, 256, 0, stream>>>(partA, partP, means, tab, c_q, c_k);
  sign8_kernel<<<2048, 256, 0, stream>>>(x, Xs, M * C / 8, c_inq);
  sign8_kernel<<<1024, 256, 0, stream>>>(qkv_w, Wqs, O3C * C / 8, nullptr);
  sign8_kernel<<<512, 256, 0, stream>>>(proj_w, Wps, C * C / 8, nullptr);
  gemm1_kernel<<<NXBP * (O3C / 128), 256, 0, stream>>>(
      Xs, Wqs, means, c_inq, c_q, c_k, c_v1, c_v2, c_v3, movq, movk, movv, Qs, Ks, Vt);
  attn_kernel<<<8 * (BH / 8) * 13, 64, 0, stream>>>(Qs, Ks, Vt, tab, movatt, c_a1, c_a2, c_a3, c_inp, Os);
  gemm2_kernel<<<NXBP * (C / 128), 256, 0, stream>>>(
      Os, Wps, means, c_inp, proj_b, (float*)d_out);
}

// Round 11
// 199.889 us; speedup vs baseline: 1.3709x; 1.3709x over previous
//
#include <hip/hip_runtime.h>
#include <hip/hip_bf16.h>

typedef __attribute__((ext_vector_type(8))) short short8;
typedef __attribute__((ext_vector_type(4))) float f32x4;
typedef __attribute__((ext_vector_type(4))) int int4v;
typedef __attribute__((ext_vector_type(8))) char char8v;
typedef __attribute__((ext_vector_type(4), aligned(4))) unsigned int uint4a;

static constexpr int B = 64, N = 198, C = 768, H = 12, D = 64;
static constexpr int M = B * N;          // 12672 = 99*128
static constexpr int BH = B * H;         // 768
static constexpr int NPAD = 208;         // 13*16
static constexpr int ALD = 216;          // P-stripe LDS leading dim (shorts)
static constexpr int O3C = 3 * C;        // 2304 = 18*128
static constexpr int TLD = 136;          // epilogue tile stride (ushorts)
static constexpr int NXB = 99;           // M/128
static constexpr int NXBP = 104;         // padded to 13*8 for XCD affinity

// ---- workspace layout (bytes) ----
static constexpr size_t OFF_MEANS = 0;
static constexpr size_t OFF_TAB   = 256;
static constexpr size_t OFF_PARTA = 2048;
static constexpr size_t OFF_PARTP = 4096;
static constexpr size_t OFF_XS    = 8192;
static constexpr size_t SZ_XS     = (size_t)M * C;           // sign(x) i8
static constexpr size_t OFF_WQS   = OFF_XS + SZ_XS;
static constexpr size_t SZ_WQS    = (size_t)O3C * C;         // sign(qkv_w) i8
static constexpr size_t OFF_WPS   = OFF_WQS + SZ_WQS;
static constexpr size_t SZ_WPS    = (size_t)C * C;           // sign(proj_w) i8
static constexpr size_t OFF_Q     = OFF_WPS + SZ_WPS;
static constexpr size_t SZ_QK     = (size_t)BH * N * D * 2;  // bf16
static constexpr size_t OFF_K     = OFF_Q + SZ_QK;
static constexpr size_t OFF_VT    = OFF_K + SZ_QK;
static constexpr size_t SZ_VT     = (size_t)BH * D * NPAD * 2; // bf16
static constexpr size_t OFF_OS    = OFF_VT + SZ_VT;          // sign(attn_out) i8

static __device__ inline unsigned short f2bf(float x) {
  union { __hip_bfloat16 h; unsigned short u; } cv;
  cv.h = __float2bfloat16(x);
  return cv.u;
}

#define GLOAD_LDS16(g, l)                                                  \
  __builtin_amdgcn_global_load_lds(                                        \
      (const __attribute__((address_space(1))) void*)(g),                  \
      (__attribute__((address_space(3))) void*)(l), 16, 0, 0)

// ---------- mean(|W|) reduction: deterministic 2-phase ----------
__global__ void reduce_abs_kernel(const float* __restrict__ w, int n, double* __restrict__ part) {
  __shared__ double sm[256];
  double s = 0.0;
  for (int i = blockIdx.x * 256 + threadIdx.x; i < n; i += 256 * gridDim.x)
    s += (double)fabsf(w[i]);
  sm[threadIdx.x] = s;
  __syncthreads();
  for (int off = 128; off > 0; off >>= 1) {
    if (threadIdx.x < (unsigned)off) sm[threadIdx.x] += sm[threadIdx.x + off];
    __syncthreads();
  }
  if (threadIdx.x == 0) part[blockIdx.x] = sm[0];
}

__global__ void finalize_kernel(const double* __restrict__ pA, const double* __restrict__ pP,
                                double* __restrict__ means, double* __restrict__ tab,
                                const float* cq, const float* ck) {
  __shared__ double sm[256];
  int t = threadIdx.x;
  sm[t] = pA[t];
  __syncthreads();
  for (int off = 128; off > 0; off >>= 1) { if (t < off) sm[t] += sm[t + off]; __syncthreads(); }
  if (t == 0) means[0] = sm[0] / (double)((size_t)O3C * C);
  __syncthreads();
  sm[t] = pP[t];
  __syncthreads();
  for (int off = 128; off > 0; off >>= 1) { if (t < off) sm[t] += sm[t + off]; __syncthreads(); }
  if (t == 0) means[1] = sm[0] / (double)((size_t)C * C);
  double delta = (double)cq[0] * (double)ck[0] * 0.125;
  if (t < 129) tab[t] = exp((double)(t - 128) * delta);
}

// ---------- sign (binarize) to i8 {-1,0,1}, 8/thread ----------
__global__ void sign8_kernel(const float* __restrict__ x, signed char* __restrict__ out,
                             int n8, const float* alpha) {
  float a = alpha ? alpha[0] : 1.0f;
  signed char pos = (a > 0.0f) ? 1 : ((a < 0.0f) ? -1 : 0);
  signed char neg = (signed char)(-pos);
  int stride = 256 * gridDim.x;
  for (int i = blockIdx.x * 256 + threadIdx.x; i < n8; i += stride) {
    const float4* xp = (const float4*)(x + (size_t)i * 8);
    float4 u = xp[0], v = xp[1];
    float vals[8] = {u.x, u.y, u.z, u.w, v.x, v.y, v.z, v.w};
    char8v s;
#pragma unroll
    for (int j = 0; j < 8; ++j)
      s[j] = vals[j] > 0.0f ? pos : (vals[j] < 0.0f ? neg : (signed char)0);
    *(char8v*)(out + (size_t)i * 8) = s;
  }
}

// XCD-affinity decode: all y-blocks of an x-tile share lin%8 -> same XCD.
static __device__ inline bool xcd_decode(int lin, int nyb, int& x, int& y) {
  int k = lin & 7;
  int q = lin >> 3;
  int xi = q / nyb;
  y = q - xi * nyb;
  x = xi * 8 + k;
  return x < NXB;
}

// ---------- staged i8 GEMM with 2-phase double buffer (T3 minimum recipe) ----------
// LDS linear dest; global SOURCE pre-swizzled (chunk cwl holds cwl^(row&7));
// read applies the same XOR -> both-sides swizzle preserved.
static __device__ inline void stage_i8(const signed char* __restrict__ A,
                                       const signed char* __restrict__ Bmat,
                                       int i0, int o0, int k0,
                                       char* AsB, char* BsB) {
  int tid = threadIdx.x;
  int lane = tid & 63, w = tid >> 6;
#pragma unroll
  for (int c = 0; c < 4; ++c) {
    int ccb = w * 64 + c * 256;          // wave-uniform 16B-chunk base
    int cc = ccb + lane;
    int row = cc >> 3, cwl = cc & 7;
    int sc16 = (cwl ^ (row & 7)) * 16;   // inverse-swizzled source byte offset
    GLOAD_LDS16(&A[(size_t)(i0 + row) * C + k0 + sc16], AsB + (size_t)ccb * 16);
    GLOAD_LDS16(&Bmat[(size_t)(o0 + row) * C + k0 + sc16], BsB + (size_t)ccb * 16);
  }
}

static __device__ inline void compute_i8(const signed char (*As)[128],
                                         const signed char (*Bs)[128],
                                         int4v acc[4][4]) {
  int lane = threadIdx.x & 63, w = threadIdx.x >> 6, wr = w >> 1, wc = w & 1;
#pragma unroll
  for (int kk = 0; kk < 2; ++kk) {
    int4v af[4], bf[4];
    int g = kk * 4 + (lane >> 4);
#pragma unroll
    for (int m = 0; m < 4; ++m) {
      int row = wr * 64 + m * 16 + (lane & 15);
      af[m] = *(const int4v*)&As[row][((g ^ (row & 7))) * 16];
    }
#pragma unroll
    for (int n2 = 0; n2 < 4; ++n2) {
      int row = wc * 64 + n2 * 16 + (lane & 15);
      bf[n2] = *(const int4v*)&Bs[row][((g ^ (row & 7))) * 16];
    }
    __builtin_amdgcn_s_setprio(1);
#pragma unroll
    for (int m = 0; m < 4; ++m)
#pragma unroll
      for (int n2 = 0; n2 < 4; ++n2)
        acc[m][n2] = __builtin_amdgcn_mfma_i32_16x16x64_i8(af[m], bf[n2], acc[m][n2], 0, 0, 0);
    __builtin_amdgcn_s_setprio(0);
  }
}

// buf layout in 64KB smem: A0@0, B0@16K, A1@32K, B1@48K.
static __device__ inline void gemm_dbuf_i8(const signed char* __restrict__ A,
                                           const signed char* __restrict__ Bmat,
                                           int i0, int o0, char* smem, int4v acc[4][4]) {
  stage_i8(A, Bmat, i0, o0, 0, smem, smem + 16384);
  asm volatile("s_waitcnt vmcnt(0)" ::: "memory");
  __builtin_amdgcn_s_barrier();
#pragma unroll
  for (int t = 0; t < 6; ++t) {
    const int cu = t & 1;                 // compile-time under full unroll
    if (t < 5)
      stage_i8(A, Bmat, i0, o0, (t + 1) * 128,
               smem + (cu ^ 1) * 32768, smem + (cu ^ 1) * 32768 + 16384);
    compute_i8((const signed char(*)[128])(smem + cu * 32768),
               (const signed char(*)[128])(smem + cu * 32768 + 16384), acc);
    asm volatile("s_waitcnt vmcnt(0)" ::: "memory");
    __builtin_amdgcn_s_barrier();
  }
}

// ---------- GEMM1: qkv = sign(x) @ sign(Wqkv)^T ----------
__global__ __launch_bounds__(256) void gemm1_kernel(
    const signed char* __restrict__ Xs, const signed char* __restrict__ Wqs,
    const double* __restrict__ means,
    const float* cin, const float* cq, const float* ck,
    const float* cv1, const float* cv2, const float* cv3,
    const float* __restrict__ movq, const float* __restrict__ movk, const float* __restrict__ movv,
    unsigned short* __restrict__ Qs, unsigned short* __restrict__ Ks, unsigned short* __restrict__ Vt) {
  int bx, by;
  if (!xcd_decode(blockIdx.x, O3C / 128, bx, by)) return;
  __shared__ __align__(16) char smem[65536];             // dbuf staging; epilogue tile aliases
  unsigned short* tile = (unsigned short*)smem;          // [128][TLD] = 34816 B
  int4v acc[4][4] = {};
  int i0 = bx * 128, o0 = by * 128;
  gemm_dbuf_i8(Xs, Wqs, i0, o0, smem, acc);
  int tid = threadIdx.x;
  int lane = tid & 63, w = tid >> 6, wr = w >> 1, wc = w & 1;
  double cw_ = (double)cin[0] * means[0];
  float dq = cq[0], dk = ck[0];
  float sq = dq > 0.0f ? 1.0f : (dq < 0.0f ? -1.0f : 0.0f);
  float sk = dk > 0.0f ? 1.0f : (dk < 0.0f ? -1.0f : 0.0f);
  double aa1 = fabs((double)cv1[0]), aa2 = fabs((double)cv2[0]), aa3 = fabs((double)cv3[0]);
  int t = o0 / C;
  int rem0 = o0 - t * C;
  float sgn = t == 0 ? sq : sk;
  const float* mov = t == 0 ? movq : (t == 1 ? movk : movv);
#pragma unroll
  for (int m = 0; m < 4; ++m)
#pragma unroll
    for (int n2 = 0; n2 < 4; ++n2)
#pragma unroll
      for (int r = 0; r < 4; ++r) {
        int rowL = wr * 64 + m * 16 + (lane >> 4) * 4 + r;
        int colL = wc * 64 + n2 * 16 + (lane & 15);
        int rem = rem0 + colL;
        int h = rem >> 6, d = rem & 63;
        double g = (double)acc[m][n2][r] * cw_;
        if (t < 2) {
          double v = g + (double)mov[h * D + d];
          float s = v > 0.0 ? sgn : (v < 0.0 ? -sgn : 0.0f);
          tile[rowL * TLD + colL] = f2bf(s);
        } else {
          double rr = g + (double)mov[h * D + d];
          double b1 = rr > 0.0 ? aa1 : (rr < 0.0 ? -aa1 : 0.0);
          rr -= b1;
          double b2 = rr > 0.0 ? aa2 : (rr < 0.0 ? -aa2 : 0.0);
          rr -= b2;
          double b3 = rr > 0.0 ? aa3 : (rr < 0.0 ? -aa3 : 0.0);
          tile[colL * TLD + rowL] = f2bf((float)(b1 + b2 + b3));  // transposed
        }
      }
  __syncthreads();
  if (t < 2) {
    unsigned short* dst = t == 0 ? Qs : Ks;
#pragma unroll
    for (int it = 0; it < 8; ++it) {
      int c = tid + it * 256;
      int rowL = c >> 4, cch = c & 15;
      int gr = i0 + rowL;
      int b = gr / N, nn = gr - b * N;
      int rem = rem0 + cch * 8;
      int h = rem >> 6, d = rem & 63;
      uint4a vdata = *(const uint4a*)&tile[rowL * TLD + cch * 8];
      *(uint4a*)&dst[((size_t)(b * H + h) * N + nn) * D + d] = vdata;
    }
  } else {
#pragma unroll
    for (int it = 0; it < 8; ++it) {
      int c = tid + it * 256;
      int colL = c >> 4, tch = c & 15;
      int rem = rem0 + colL;
      int h = rem >> 6, d = rem & 63;
      int gr0 = i0 + tch * 8;
      int b0 = gr0 / N, nn0 = gr0 - b0 * N;
      uint4a vdata = *(const uint4a*)&tile[colL * TLD + tch * 8];
      if (nn0 + 8 <= N) {
        *(uint4a*)&Vt[((size_t)(b0 * H + h) * D + d) * NPAD + nn0] = vdata;
      } else {
        const unsigned short* pv = (const unsigned short*)&vdata;
#pragma unroll
        for (int j = 0; j < 8; ++j) {
          int gr = gr0 + j;
          int b = gr / N, nn = gr - b * N;
          Vt[((size_t)(b * H + h) * D + d) * NPAD + nn] = pv[j];
        }
      }
    }
  }
}

// ---------- fused attention v4: 1 wave per (rt, bh), XCD-aware placement ----------
__global__ __launch_bounds__(64) void attn_kernel(
    const unsigned short* __restrict__ Qs, const unsigned short* __restrict__ Ks,
    const unsigned short* __restrict__ Vt, const double* __restrict__ tab,
    const float* __restrict__ movatt,
    const float* ca1p, const float* ca2p, const float* ca3p, const float* cipp,
    signed char* __restrict__ Os) {
  __shared__ double tabl[132];
  __shared__ unsigned short Al[16 * ALD];
  int i = blockIdx.x;
  int xcd = i & 7;
  int j = i >> 3;
  int rt = j % 13;
  int bh = (j / 13) * 8 + xcd;   // bh % 8 == i % 8
  int b = bh / H, h = bh - b * H;
  int lane = threadIdx.x;
  int g = lane >> 4, q16 = lane & 15;
  for (int ii = lane; ii < 129; ii += 64) tabl[ii] = tab[ii];
  __syncthreads();
  double ca1 = (double)ca1p[0], ca2 = (double)ca2p[0], ca3 = (double)ca3p[0];
  double t1 = 0.5 * ca1, t2 = 0.5 * ca2, t3 = 0.5 * ca3;
  float cip = cipp[0];
  float sgn_cip = cip > 0.0f ? 1.0f : (cip < 0.0f ? -1.0f : 0.0f);

  short8 qf[2];
  int qrow = rt * 16 + q16;
#pragma unroll
  for (int kk = 0; kk < 2; ++kk) {
    short8 z = {};
    qf[kk] = (qrow < N)
        ? *(const short8*)&Qs[((size_t)bh * N + qrow) * D + kk * 32 + g * 8]
        : z;
  }
  f32x4 sacc[13] = {};
#pragma unroll
  for (int kk = 0; kk < 2; ++kk)
#pragma unroll
    for (int ct = 0; ct < 13; ++ct) {
      int krow = ct * 16 + q16;
      short8 z = {};
      short8 kf = (krow < N)
          ? *(const short8*)&Ks[((size_t)bh * N + krow) * D + kk * 32 + g * 8]
          : z;
      sacc[ct] = __builtin_amdgcn_mfma_f32_16x16x32_bf16(qf[kk], kf, sacc[ct], 0, 0, 0);
    }
#pragma unroll
  for (int r = 0; r < 4; ++r) {
    int rowg = rt * 16 + g * 4 + r;
    int rowc = rowg < N ? rowg : N - 1;
    const float* mrow = movatt + ((size_t)h * N + rowc) * N;
    float mx = -3.0e38f;
#pragma unroll
    for (int ct = 0; ct < 13; ++ct) {
      int colc = ct * 16 + q16;
      if (colc < N) mx = fmaxf(mx, sacc[ct][r]);
    }
    mx = fmaxf(mx, __shfl_xor(mx, 1));
    mx = fmaxf(mx, __shfl_xor(mx, 2));
    mx = fmaxf(mx, __shfl_xor(mx, 4));
    mx = fmaxf(mx, __shfl_xor(mx, 8));
    double ev[13];
    double ssum = 0.0;
#pragma unroll
    for (int ct = 0; ct < 13; ++ct) {
      int colc = ct * 16 + q16;
      int idx = (int)(sacc[ct][r] - mx) + 128;
      double e = (colc < N) ? tabl[idx] : 0.0;
      ev[ct] = e;
      ssum += e;
    }
    ssum += __shfl_xor(ssum, 1);
    ssum += __shfl_xor(ssum, 2);
    ssum += __shfl_xor(ssum, 4);
    ssum += __shfl_xor(ssum, 8);
    double rec = 1.0 / ssum;
#pragma unroll
    for (int ct = 0; ct < 13; ++ct) {
      int colc = ct * 16 + q16;
      int colb = colc < N ? colc : N - 1;
      double at = ev[ct] * rec + (double)mrow[colb];
      double b1 = at > t1 ? ca1 : 0.0;
      double rr = at - b1;
      double b2 = rr > t2 ? ca2 : 0.0;
      rr -= b2;
      double b3 = rr > t3 ? ca3 : 0.0;
      float av = (colc < N) ? (float)(b1 + b2 + b3) : 0.0f;
      Al[(g * 4 + r) * ALD + colc] = f2bf(av);
    }
  }
  __syncthreads();
  f32x4 oacc[4] = {};
#pragma unroll
  for (int kt = 0; kt < 7; ++kt) {
    int kbase = kt * 32 + g * 8;
    short8 z = {};
    short8 af = (kbase < NPAD) ? *(const short8*)&Al[q16 * ALD + kbase] : z;
    int kb2 = kbase < NPAD ? kbase : 0;
#pragma unroll
    for (int dt = 0; dt < 4; ++dt) {
      short8 bv = *(const short8*)&Vt[((size_t)bh * 64 + dt * 16 + q16) * NPAD + kb2];
      oacc[dt] = __builtin_amdgcn_mfma_f32_16x16x32_bf16(af, bv, oacc[dt], 0, 0, 0);
    }
  }
#pragma unroll
  for (int dt = 0; dt < 4; ++dt)
#pragma unroll
    for (int r = 0; r < 4; ++r) {
      int rowg = rt * 16 + g * 4 + r;
      if (rowg < N) {
        int d = dt * 16 + q16;
        float v = oacc[dt][r];
        float s = v > 0.0f ? sgn_cip : (v < 0.0f ? -sgn_cip : 0.0f);
        Os[((size_t)(b * N + rowg)) * C + h * D + d] =
            (signed char)(s > 0.0f ? 1 : (s < 0.0f ? -1 : 0));
      }
    }
}

// ---------- GEMM2: out = (cip*sign) @ sign(Wp)^T * wbar + bias -> f32 ----------
__global__ __launch_bounds__(256) void gemm2_kernel(
    const signed char* __restrict__ Os, const signed char* __restrict__ Wps,
    const double* __restrict__ means, const float* cip, const float* __restrict__ proj_b,
    float* __restrict__ out) {
  int bx, by;
  if (!xcd_decode(blockIdx.x, C / 128, bx, by)) return;
  __shared__ __align__(16) char smem[65536];
  int4v acc[4][4] = {};
  int i0 = bx * 128, o0 = by * 128;
  gemm_dbuf_i8(Os, Wps, i0, o0, smem, acc);
  int lane = threadIdx.x & 63, w = threadIdx.x >> 6, wr = w >> 1, wc = w & 1;
  double cw_ = (double)cip[0] * means[1];
#pragma unroll
  for (int m = 0; m < 4; ++m)
#pragma unroll
    for (int n2 = 0; n2 < 4; ++n2)
#pragma unroll
      for (int r = 0; r < 4; ++r) {
        int row = i0 + wr * 64 + m * 16 + (lane >> 4) * 4 + r;
        int col = o0 + wc * 64 + n2 * 16 + (lane & 15);
        double v = (double)acc[m][n2][r] * cw_ + (double)proj_b[col];
        out[(size_t)row * C + col] = (float)v;
      }
}

extern "C" void kernel_launch(void* const* d_in, const int* in_sizes, int n_in,
                              void* d_out, int out_size, void* d_ws, size_t ws_size,
                              hipStream_t stream) {
  const float* x      = (const float*)d_in[0];
  const float* qkv_w  = (const float*)d_in[1];
  const float* proj_w = (const float*)d_in[2];
  const float* proj_b = (const float*)d_in[3];
  const float* movq   = (const float*)d_in[4];
  const float* movk   = (const float*)d_in[5];
  const float* movv   = (const float*)d_in[6];
  const float* movatt = (const float*)d_in[7];
  const float* c_inq  = (const float*)d_in[8];
  const float* c_q    = (const float*)d_in[9];
  const float* c_k    = (const float*)d_in[10];
  const float* c_v1   = (const float*)d_in[11];
  const float* c_v2   = (const float*)d_in[12];
  const float* c_v3   = (const float*)d_in[13];
  const float* c_a1   = (const float*)d_in[14];
  const float* c_a2   = (const float*)d_in[15];
  const float* c_a3   = (const float*)d_in[16];
  const float* c_inp  = (const float*)d_in[17];

  char* ws = (char*)d_ws;
  double* means = (double*)(ws + OFF_MEANS);
  double* tab   = (double*)(ws + OFF_TAB);
  double* partA = (double*)(ws + OFF_PARTA);
  double* partP = (double*)(ws + OFF_PARTP);
  signed char* Xs  = (signed char*)(ws + OFF_XS);
  signed char* Wqs = (signed char*)(ws + OFF_WQS);
  signed char* Wps = (signed char*)(ws + OFF_WPS);
  unsigned short* Qs  = (unsigned short*)(ws + OFF_Q);
  unsigned short* Ks  = (unsigned short*)(ws + OFF_K);
  unsigned short* Vt  = (unsigned short*)(ws + OFF_VT);
  signed char* Os  = (signed char*)(ws + OFF_OS);

  reduce_abs_kernel<<<256, 256, 0, stream>>>(qkv_w, O3C * C, partA);
  reduce_abs_kernel<<<256, 256, 0, stream>>>(proj_w, C * C, partP);
  finalize_kernel<<<1, 256, 0, stream>>>(partA, partP, means, tab, c_q, c_k);
  sign8_kernel<<<2048, 256, 0, stream>>>(x, Xs, M * C / 8, c_inq);
  sign8_kernel<<<1024, 256, 0, stream>>>(qkv_w, Wqs, O3C * C / 8, nullptr);
  sign8_kernel<<<512, 256, 0, stream>>>(proj_w, Wps, C * C / 8, nullptr);
  gemm1_kernel<<<NXBP * (O3C / 128), 256, 0, stream>>>(
      Xs, Wqs, means, c_inq, c_q, c_k, c_v1, c_v2, c_v3, movq, movk, movv, Qs, Ks, Vt);
  attn_kernel<<<8 * (BH / 8) * 13, 64, 0, stream>>>(Qs, Ks, Vt, tab, movatt, c_a1, c_a2, c_a3, c_inp, Os);
  gemm2_kernel<<<NXBP * (C / 128), 256, 0, stream>>>(
      Os, Wps, means, c_inp, proj_b, (float*)d_out);
}

// Round 12
// 198.886 us; speedup vs baseline: 1.3779x; 1.0050x over previous
//
#include <hip/hip_runtime.h>
#include <hip/hip_bf16.h>

typedef __attribute__((ext_vector_type(8))) short short8;
typedef __attribute__((ext_vector_type(4))) float f32x4;
typedef __attribute__((ext_vector_type(4))) int int4v;
typedef __attribute__((ext_vector_type(8))) char char8v;
typedef __attribute__((ext_vector_type(4), aligned(4))) unsigned int uint4a;

static constexpr int B = 64, N = 198, C = 768, H = 12, D = 64;
static constexpr int M = B * N;          // 12672 = 99*128
static constexpr int BH = B * H;         // 768
static constexpr int NPAD = 208;         // 13*16
static constexpr int ALD = 216;          // P-stripe LDS leading dim (shorts)
static constexpr int O3C = 3 * C;        // 2304 = 18*128
static constexpr int TLD = 136;          // epilogue tile stride (ushorts)
static constexpr int NXB = 99;           // M/128
static constexpr int NXBP = 104;         // padded to 13*8 for XCD affinity

// ---- workspace layout (bytes) ----
static constexpr size_t OFF_MEANS = 0;
static constexpr size_t OFF_TAB   = 256;
static constexpr size_t OFF_PARTA = 2048;
static constexpr size_t OFF_PARTP = 4096;
static constexpr size_t OFF_XS    = 8192;
static constexpr size_t SZ_XS     = (size_t)M * C;           // sign(x) i8
static constexpr size_t OFF_WQS   = OFF_XS + SZ_XS;
static constexpr size_t SZ_WQS    = (size_t)O3C * C;         // sign(qkv_w) i8
static constexpr size_t OFF_WPS   = OFF_WQS + SZ_WQS;
static constexpr size_t SZ_WPS    = (size_t)C * C;           // sign(proj_w) i8
static constexpr size_t OFF_Q     = OFF_WPS + SZ_WPS;
static constexpr size_t SZ_QK     = (size_t)BH * N * D * 2;  // bf16
static constexpr size_t OFF_K     = OFF_Q + SZ_QK;
static constexpr size_t OFF_VT    = OFF_K + SZ_QK;
static constexpr size_t SZ_VT     = (size_t)BH * D * NPAD * 2; // bf16
static constexpr size_t OFF_OS    = OFF_VT + SZ_VT;          // sign(attn_out) i8

static __device__ inline unsigned short f2bf(float x) {
  union { __hip_bfloat16 h; unsigned short u; } cv;
  cv.h = __float2bfloat16(x);
  return cv.u;
}

#define GLOAD_LDS16(g, l)                                                  \
  __builtin_amdgcn_global_load_lds(                                        \
      (const __attribute__((address_space(1))) void*)(g),                  \
      (__attribute__((address_space(3))) void*)(l), 16, 0, 0)

// ---------- mean(|W|) reduction: deterministic 2-phase ----------
__global__ void reduce_abs_kernel(const float* __restrict__ w, int n, double* __restrict__ part) {
  __shared__ double sm[256];
  double s = 0.0;
  for (int i = blockIdx.x * 256 + threadIdx.x; i < n; i += 256 * gridDim.x)
    s += (double)fabsf(w[i]);
  sm[threadIdx.x] = s;
  __syncthreads();
  for (int off = 128; off > 0; off >>= 1) {
    if (threadIdx.x < (unsigned)off) sm[threadIdx.x] += sm[threadIdx.x + off];
    __syncthreads();
  }
  if (threadIdx.x == 0) part[blockIdx.x] = sm[0];
}

__global__ void finalize_kernel(const double* __restrict__ pA, const double* __restrict__ pP,
                                double* __restrict__ means, double* __restrict__ tab,
                                const float* cq, const float* ck) {
  __shared__ double sm[256];
  int t = threadIdx.x;
  sm[t] = pA[t];
  __syncthreads();
  for (int off = 128; off > 0; off >>= 1) { if (t < off) sm[t] += sm[t + off]; __syncthreads(); }
  if (t == 0) means[0] = sm[0] / (double)((size_t)O3C * C);
  __syncthreads();
  sm[t] = pP[t];
  __syncthreads();
  for (int off = 128; off > 0; off >>= 1) { if (t < off) sm[t] += sm[t + off]; __syncthreads(); }
  if (t == 0) means[1] = sm[0] / (double)((size_t)C * C);
  double delta = (double)cq[0] * (double)ck[0] * 0.125;
  if (t < 129) tab[t] = exp((double)(t - 128) * delta);
}

// ---------- sign (binarize) to i8 {-1,0,1}, 8/thread ----------
__global__ void sign8_kernel(const float* __restrict__ x, signed char* __restrict__ out,
                             int n8, const float* alpha) {
  float a = alpha ? alpha[0] : 1.0f;
  signed char pos = (a > 0.0f) ? 1 : ((a < 0.0f) ? -1 : 0);
  signed char neg = (signed char)(-pos);
  int stride = 256 * gridDim.x;
  for (int i = blockIdx.x * 256 + threadIdx.x; i < n8; i += stride) {
    const float4* xp = (const float4*)(x + (size_t)i * 8);
    float4 u = xp[0], v = xp[1];
    float vals[8] = {u.x, u.y, u.z, u.w, v.x, v.y, v.z, v.w};
    char8v s;
#pragma unroll
    for (int j = 0; j < 8; ++j)
      s[j] = vals[j] > 0.0f ? pos : (vals[j] < 0.0f ? neg : (signed char)0);
    *(char8v*)(out + (size_t)i * 8) = s;
  }
}

// XCD-affinity decode: all y-blocks of an x-tile share lin%8 -> same XCD.
static __device__ inline bool xcd_decode(int lin, int nyb, int& x, int& y) {
  int k = lin & 7;
  int q = lin >> 3;
  int xi = q / nyb;
  y = q - xi * nyb;
  x = xi * 8 + k;
  return x < NXB;
}

// ---------- staged i8 GEMM with 2-phase double buffer (T3 minimum recipe) ----------
static __device__ inline void stage_i8(const signed char* __restrict__ A,
                                       const signed char* __restrict__ Bmat,
                                       int i0, int o0, int k0,
                                       char* AsB, char* BsB) {
  int tid = threadIdx.x;
  int lane = tid & 63, w = tid >> 6;
#pragma unroll
  for (int c = 0; c < 4; ++c) {
    int ccb = w * 64 + c * 256;          // wave-uniform 16B-chunk base
    int cc = ccb + lane;
    int row = cc >> 3, cwl = cc & 7;
    int sc16 = (cwl ^ (row & 7)) * 16;   // inverse-swizzled source byte offset
    GLOAD_LDS16(&A[(size_t)(i0 + row) * C + k0 + sc16], AsB + (size_t)ccb * 16);
    GLOAD_LDS16(&Bmat[(size_t)(o0 + row) * C + k0 + sc16], BsB + (size_t)ccb * 16);
  }
}

static __device__ inline void compute_i8(const signed char (*As)[128],
                                         const signed char (*Bs)[128],
                                         int4v acc[4][4]) {
  int lane = threadIdx.x & 63, w = threadIdx.x >> 6, wr = w >> 1, wc = w & 1;
#pragma unroll
  for (int kk = 0; kk < 2; ++kk) {
    int4v af[4], bf[4];
    int g = kk * 4 + (lane >> 4);
#pragma unroll
    for (int m = 0; m < 4; ++m) {
      int row = wr * 64 + m * 16 + (lane & 15);
      af[m] = *(const int4v*)&As[row][((g ^ (row & 7))) * 16];
    }
#pragma unroll
    for (int n2 = 0; n2 < 4; ++n2) {
      int row = wc * 64 + n2 * 16 + (lane & 15);
      bf[n2] = *(const int4v*)&Bs[row][((g ^ (row & 7))) * 16];
    }
    __builtin_amdgcn_s_setprio(1);
#pragma unroll
    for (int m = 0; m < 4; ++m)
#pragma unroll
      for (int n2 = 0; n2 < 4; ++n2)
        acc[m][n2] = __builtin_amdgcn_mfma_i32_16x16x64_i8(af[m], bf[n2], acc[m][n2], 0, 0, 0);
    __builtin_amdgcn_s_setprio(0);
  }
}

// buf layout in 64KB smem: A0@0, B0@16K, A1@32K, B1@48K.
static __device__ inline void gemm_dbuf_i8(const signed char* __restrict__ A,
                                           const signed char* __restrict__ Bmat,
                                           int i0, int o0, char* smem, int4v acc[4][4]) {
  stage_i8(A, Bmat, i0, o0, 0, smem, smem + 16384);
  asm volatile("s_waitcnt vmcnt(0)" ::: "memory");
  __builtin_amdgcn_s_barrier();
#pragma unroll
  for (int t = 0; t < 6; ++t) {
    const int cu = t & 1;                 // compile-time under full unroll
    if (t < 5)
      stage_i8(A, Bmat, i0, o0, (t + 1) * 128,
               smem + (cu ^ 1) * 32768, smem + (cu ^ 1) * 32768 + 16384);
    compute_i8((const signed char(*)[128])(smem + cu * 32768),
               (const signed char(*)[128])(smem + cu * 32768 + 16384), acc);
    asm volatile("s_waitcnt vmcnt(0)" ::: "memory");
    __builtin_amdgcn_s_barrier();
  }
}

// ---------- GEMM1: qkv = sign(x) @ sign(Wqkv)^T ----------
__global__ __launch_bounds__(256) void gemm1_kernel(
    const signed char* __restrict__ Xs, const signed char* __restrict__ Wqs,
    const double* __restrict__ means,
    const float* cin, const float* cq, const float* ck,
    const float* cv1, const float* cv2, const float* cv3,
    const float* __restrict__ movq, const float* __restrict__ movk, const float* __restrict__ movv,
    unsigned short* __restrict__ Qs, unsigned short* __restrict__ Ks, unsigned short* __restrict__ Vt) {
  int bx, by;
  if (!xcd_decode(blockIdx.x, O3C / 128, bx, by)) return;
  __shared__ __align__(16) char smem[65536];             // dbuf staging; epilogue tile aliases
  unsigned short* tile = (unsigned short*)smem;          // [128][TLD] = 34816 B
  int4v acc[4][4] = {};
  int i0 = bx * 128, o0 = by * 128;
  gemm_dbuf_i8(Xs, Wqs, i0, o0, smem, acc);
  int tid = threadIdx.x;
  int lane = tid & 63, w = tid >> 6, wr = w >> 1, wc = w & 1;
  double cw_ = (double)cin[0] * means[0];
  float dq = cq[0], dk = ck[0];
  float sq = dq > 0.0f ? 1.0f : (dq < 0.0f ? -1.0f : 0.0f);
  float sk = dk > 0.0f ? 1.0f : (dk < 0.0f ? -1.0f : 0.0f);
  double aa1 = fabs((double)cv1[0]), aa2 = fabs((double)cv2[0]), aa3 = fabs((double)cv3[0]);
  int t = o0 / C;
  int rem0 = o0 - t * C;
  float sgn = t == 0 ? sq : sk;
  const float* mov = t == 0 ? movq : (t == 1 ? movk : movv);
#pragma unroll
  for (int m = 0; m < 4; ++m)
#pragma unroll
    for (int n2 = 0; n2 < 4; ++n2)
#pragma unroll
      for (int r = 0; r < 4; ++r) {
        int rowL = wr * 64 + m * 16 + (lane >> 4) * 4 + r;
        int colL = wc * 64 + n2 * 16 + (lane & 15);
        int rem = rem0 + colL;
        int h = rem >> 6, d = rem & 63;
        double g = (double)acc[m][n2][r] * cw_;
        if (t < 2) {
          double v = g + (double)mov[h * D + d];
          float s = v > 0.0 ? sgn : (v < 0.0 ? -sgn : 0.0f);
          tile[rowL * TLD + colL] = f2bf(s);
        } else {
          double rr = g + (double)mov[h * D + d];
          double b1 = rr > 0.0 ? aa1 : (rr < 0.0 ? -aa1 : 0.0);
          rr -= b1;
          double b2 = rr > 0.0 ? aa2 : (rr < 0.0 ? -aa2 : 0.0);
          rr -= b2;
          double b3 = rr > 0.0 ? aa3 : (rr < 0.0 ? -aa3 : 0.0);
          tile[colL * TLD + rowL] = f2bf((float)(b1 + b2 + b3));  // transposed
        }
      }
  __syncthreads();
  if (t < 2) {
    unsigned short* dst = t == 0 ? Qs : Ks;
#pragma unroll
    for (int it = 0; it < 8; ++it) {
      int c = tid + it * 256;
      int rowL = c >> 4, cch = c & 15;
      int gr = i0 + rowL;
      int b = gr / N, nn = gr - b * N;
      int rem = rem0 + cch * 8;
      int h = rem >> 6, d = rem & 63;
      uint4a vdata = *(const uint4a*)&tile[rowL * TLD + cch * 8];
      *(uint4a*)&dst[((size_t)(b * H + h) * N + nn) * D + d] = vdata;
    }
  } else {
#pragma unroll
    for (int it = 0; it < 8; ++it) {
      int c = tid + it * 256;
      int colL = c >> 4, tch = c & 15;
      int rem = rem0 + colL;
      int h = rem >> 6, d = rem & 63;
      int gr0 = i0 + tch * 8;
      int b0 = gr0 / N, nn0 = gr0 - b0 * N;
      uint4a vdata = *(const uint4a*)&tile[colL * TLD + tch * 8];
      if (nn0 + 8 <= N) {
        *(uint4a*)&Vt[((size_t)(b0 * H + h) * D + d) * NPAD + nn0] = vdata;
      } else {
        const unsigned short* pv = (const unsigned short*)&vdata;
#pragma unroll
        for (int j = 0; j < 8; ++j) {
          int gr = gr0 + j;
          int b = gr / N, nn = gr - b * N;
          Vt[((size_t)(b * H + h) * D + d) * NPAD + nn] = pv[j];
        }
      }
    }
  }
}

// ---------- fused attention v5: 4 independent waves per block, XCD-affine ----------
// Block i: xcd=i&7, q=i>>3, rt=q%13, grp=q/13 (0..23). Wave w handles
// bh=(grp*4+w)*8+xcd -> all four bh share bh%8==xcd (same-XCD K/V/movatt),
// and all 13 rt-blocks of each bh stay on that XCD. Same 9984 waves as v4
// but 4 waves per workgroup slot -> higher residency.
__global__ __launch_bounds__(256) void attn_kernel(
    const unsigned short* __restrict__ Qs, const unsigned short* __restrict__ Ks,
    const unsigned short* __restrict__ Vt, const double* __restrict__ tab,
    const float* __restrict__ movatt,
    const float* ca1p, const float* ca2p, const float* ca3p, const float* cipp,
    signed char* __restrict__ Os) {
  __shared__ double tabl[132];
  __shared__ unsigned short Al[4][16 * ALD];
  int i = blockIdx.x;
  int xcd = i & 7;
  int q = i >> 3;
  int rt = q % 13;
  int grp = q / 13;              // 0..23
  int tid = threadIdx.x;
  int w = tid >> 6, lane = tid & 63;
  int bh = (grp * 4 + w) * 8 + xcd;
  int b = bh / H, h = bh - b * H;
  int g = lane >> 4, q16 = lane & 15;
  for (int ii = tid; ii < 129; ii += 256) tabl[ii] = tab[ii];
  __syncthreads();
  double ca1 = (double)ca1p[0], ca2 = (double)ca2p[0], ca3 = (double)ca3p[0];
  double t1 = 0.5 * ca1, t2 = 0.5 * ca2, t3 = 0.5 * ca3;
  float cip = cipp[0];
  float sgn_cip = cip > 0.0f ? 1.0f : (cip < 0.0f ? -1.0f : 0.0f);

  // --- Q fragments (rows >=198 zero) ---
  short8 qf[2];
  int qrow = rt * 16 + q16;
#pragma unroll
  for (int kk = 0; kk < 2; ++kk) {
    short8 z = {};
    qf[kk] = (qrow < N)
        ? *(const short8*)&Qs[((size_t)bh * N + qrow) * D + kk * 32 + g * 8]
        : z;
  }
  // --- S = Q K^T (exact integers in f32) ---
  f32x4 sacc[13] = {};
#pragma unroll
  for (int kk = 0; kk < 2; ++kk)
#pragma unroll
    for (int ct = 0; ct < 13; ++ct) {
      int krow = ct * 16 + q16;
      short8 z = {};
      short8 kf = (krow < N)
          ? *(const short8*)&Ks[((size_t)bh * N + krow) * D + kk * 32 + g * 8]
          : z;
      sacc[ct] = __builtin_amdgcn_mfma_f32_16x16x32_bf16(qf[kk], kf, sacc[ct], 0, 0, 0);
    }
  // --- softmax (f64 exp table) + bias + gsb_bin01 (compare form) ---
#pragma unroll
  for (int r = 0; r < 4; ++r) {
    int rowg = rt * 16 + g * 4 + r;
    int rowc = rowg < N ? rowg : N - 1;
    const float* mrow = movatt + ((size_t)h * N + rowc) * N;
    float mx = -3.0e38f;
#pragma unroll
    for (int ct = 0; ct < 13; ++ct) {
      int colc = ct * 16 + q16;
      if (colc < N) mx = fmaxf(mx, sacc[ct][r]);
    }
    mx = fmaxf(mx, __shfl_xor(mx, 1));
    mx = fmaxf(mx, __shfl_xor(mx, 2));
    mx = fmaxf(mx, __shfl_xor(mx, 4));
    mx = fmaxf(mx, __shfl_xor(mx, 8));
    double ssum = 0.0;
#pragma unroll
    for (int ct = 0; ct < 13; ++ct) {
      int colc = ct * 16 + q16;
      int idx = (int)(sacc[ct][r] - mx) + 128;
      ssum += (colc < N) ? tabl[idx] : 0.0;
    }
    ssum += __shfl_xor(ssum, 1);
    ssum += __shfl_xor(ssum, 2);
    ssum += __shfl_xor(ssum, 4);
    ssum += __shfl_xor(ssum, 8);
    double rec = 1.0 / ssum;
#pragma unroll
    for (int ct = 0; ct < 13; ++ct) {
      int colc = ct * 16 + q16;
      int colb = colc < N ? colc : N - 1;
      int idx = (int)(sacc[ct][r] - mx) + 128;
      double e = (colc < N) ? tabl[idx] : 0.0;   // re-read: saves ev[13] VGPRs
      double at = e * rec + (double)mrow[colb];
      double b1 = at > t1 ? ca1 : 0.0;
      double rr = at - b1;
      double b2 = rr > t2 ? ca2 : 0.0;
      rr -= b2;
      double b3 = rr > t3 ? ca3 : 0.0;
      float av = (colc < N) ? (float)(b1 + b2 + b3) : 0.0f;
      Al[w][(g * 4 + r) * ALD + colc] = f2bf(av);
    }
  }
  __builtin_amdgcn_s_barrier();   // per-wave data; barrier only orders LDS within wave's stripe
  // --- PV: out[16,64] = P[16,208] @ V[208,64] ---
  f32x4 oacc[4] = {};
#pragma unroll
  for (int kt = 0; kt < 7; ++kt) {
    int kbase = kt * 32 + g * 8;
    short8 z = {};
    short8 af = (kbase < NPAD) ? *(const short8*)&Al[w][q16 * ALD + kbase] : z;
    int kb2 = kbase < NPAD ? kbase : 0;
#pragma unroll
    for (int dt = 0; dt < 4; ++dt) {
      short8 bv = *(const short8*)&Vt[((size_t)bh * 64 + dt * 16 + q16) * NPAD + kb2];
      oacc[dt] = __builtin_amdgcn_mfma_f32_16x16x32_bf16(af, bv, oacc[dt], 0, 0, 0);
    }
  }
  // --- sign epilogue ---
#pragma unroll
  for (int dt = 0; dt < 4; ++dt)
#pragma unroll
    for (int r = 0; r < 4; ++r) {
      int rowg = rt * 16 + g * 4 + r;
      if (rowg < N) {
        int d = dt * 16 + q16;
        float v = oacc[dt][r];
        float s = v > 0.0f ? sgn_cip : (v < 0.0f ? -sgn_cip : 0.0f);
        Os[((size_t)(b * N + rowg)) * C + h * D + d] =
            (signed char)(s > 0.0f ? 1 : (s < 0.0f ? -1 : 0));
      }
    }
}

// ---------- GEMM2: out = (cip*sign) @ sign(Wp)^T * wbar + bias -> f32 ----------
__global__ __launch_bounds__(256) void gemm2_kernel(
    const signed char* __restrict__ Os, const signed char* __restrict__ Wps,
    const double* __restrict__ means, const float* cip, const float* __restrict__ proj_b,
    float* __restrict__ out) {
  int bx, by;
  if (!xcd_decode(blockIdx.x, C / 128, bx, by)) return;
  __shared__ __align__(16) char smem[65536];
  int4v acc[4][4] = {};
  int i0 = bx * 128, o0 = by * 128;
  gemm_dbuf_i8(Os, Wps, i0, o0, smem, acc);
  int lane = threadIdx.x & 63, w = threadIdx.x >> 6, wr = w >> 1, wc = w & 1;
  double cw_ = (double)cip[0] * means[1];
#pragma unroll
  for (int m = 0; m < 4; ++m)
#pragma unroll
    for (int n2 = 0; n2 < 4; ++n2)
#pragma unroll
      for (int r = 0; r < 4; ++r) {
        int row = i0 + wr * 64 + m * 16 + (lane >> 4) * 4 + r;
        int col = o0 + wc * 64 + n2 * 16 + (lane & 15);
        double v = (double)acc[m][n2][r] * cw_ + (double)proj_b[col];
        out[(size_t)row * C + col] = (float)v;
      }
}

extern "C" void kernel_launch(void* const* d_in, const int* in_sizes, int n_in,
                              void* d_out, int out_size, void* d_ws, size_t ws_size,
                              hipStream_t stream) {
  const float* x      = (const float*)d_in[0];
  const float* qkv_w  = (const float*)d_in[1];
  const float* proj_w = (const float*)d_in[2];
  const float* proj_b = (const float*)d_in[3];
  const float* movq   = (const float*)d_in[4];
  const float* movk   = (const float*)d_in[5];
  const float* movv   = (const float*)d_in[6];
  const float* movatt = (const float*)d_in[7];
  const float* c_inq  = (const float*)d_in[8];
  const float* c_q    = (const float*)d_in[9];
  const float* c_k    = (const float*)d_in[10];
  const float* c_v1   = (const float*)d_in[11];
  const float* c_v2   = (const float*)d_in[12];
  const float* c_v3   = (const float*)d_in[13];
  const float* c_a1   = (const float*)d_in[14];
  const float* c_a2   = (const float*)d_in[15];
  const float* c_a3   = (const float*)d_in[16];
  const float* c_inp  = (const float*)d_in[17];

  char* ws = (char*)d_ws;
  double* means = (double*)(ws + OFF_MEANS);
  double* tab   = (double*)(ws + OFF_TAB);
  double* partA = (double*)(ws + OFF_PARTA);
  double* partP = (double*)(ws + OFF_PARTP);
  signed char* Xs  = (signed char*)(ws + OFF_XS);
  signed char* Wqs = (signed char*)(ws + OFF_WQS);
  signed char* Wps = (signed char*)(ws + OFF_WPS);
  unsigned short* Qs  = (unsigned short*)(ws + OFF_Q);
  unsigned short* Ks  = (unsigned short*)(ws + OFF_K);
  unsigned short* Vt  = (unsigned short*)(ws + OFF_VT);
  signed char* Os  = (signed char*)(ws + OFF_OS);

  reduce_abs_kernel<<<256, 256, 0, stream>>>(qkv_w, O3C * C, partA);
  reduce_abs_kernel<<<256, 256, 0, stream>>>(proj_w, C * C, partP);
  finalize_kernel<<<1, 256, 0, stream>>>(partA, partP, means, tab, c_q, c_k);
  sign8_kernel<<<2048, 256, 0, stream>>>(x, Xs, M * C / 8, c_inq);
  sign8_kernel<<<1024, 256, 0, stream>>>(qkv_w, Wqs, O3C * C / 8, nullptr);
  sign8_kernel<<<512, 256, 0, stream>>>(proj_w, Wps, C * C / 8, nullptr);
  gemm1_kernel<<<NXBP * (O3C / 128), 256, 0, stream>>>(
      Xs, Wqs, means, c_inq, c_q, c_k, c_v1, c_v2, c_v3, movq, movk, movv, Qs, Ks, Vt);
  attn_kernel<<<8 * 13 * (BH / 32), 256, 0, stream>>>(Qs, Ks, Vt, tab, movatt, c_a1, c_a2, c_a3, c_inp, Os);
  gemm2_kernel<<<NXBP * (C / 128), 256, 0, stream>>>(
      Os, Wps, means, c_inp, proj_b, (float*)d_out);
}

// Round 13
// 178.326 us; speedup vs baseline: 1.5367x; 1.1153x over previous
//
#include <hip/hip_runtime.h>
#include <hip/hip_bf16.h>

typedef __attribute__((ext_vector_type(8))) short short8;
typedef __attribute__((ext_vector_type(4))) float f32x4;
typedef __attribute__((ext_vector_type(4))) int int4v;
typedef __attribute__((ext_vector_type(8))) char char8v;
typedef __attribute__((ext_vector_type(4), aligned(4))) unsigned int uint4a;

static constexpr int B = 64, N = 198, C = 768, H = 12, D = 64;
static constexpr int M = B * N;          // 12672 = 99*128
static constexpr int BH = B * H;         // 768
static constexpr int O3C = 3 * C;        // 2304 = 18*128
static constexpr int NXB = 99;           // M/128
static constexpr int TLD8 = 144;         // gemm1 epilogue i8 tile stride
static constexpr int AL8 = 272;         // attn P-stripe i8 stride
static constexpr int VNP = 256;          // V^T i8 padded cols

// ---- workspace layout (bytes) ----
static constexpr size_t OFF_MEANS = 0;
static constexpr size_t OFF_TAB   = 256;   // 129 + 16 doubles
static constexpr size_t OFF_PARTA = 2048;
static constexpr size_t OFF_PARTP = 4096;
static constexpr size_t OFF_XS    = 8192;
static constexpr size_t SZ_XS     = (size_t)M * C;           // sign(x) i8
static constexpr size_t OFF_WQS   = OFF_XS + SZ_XS;
static constexpr size_t SZ_WQS    = (size_t)O3C * C;
static constexpr size_t OFF_WPS   = OFF_WQS + SZ_WQS;
static constexpr size_t SZ_WPS    = (size_t)C * C;
static constexpr size_t OFF_Q     = OFF_WPS + SZ_WPS;
static constexpr size_t SZ_QK8    = (size_t)BH * N * D;      // i8
static constexpr size_t OFF_K     = OFF_Q + SZ_QK8;
static constexpr size_t OFF_VT    = OFF_K + SZ_QK8;
static constexpr size_t SZ_VT8    = (size_t)BH * D * VNP;    // i8, cols>=208 never written (P=0 there)
static constexpr size_t OFF_OS    = OFF_VT + SZ_VT8;         // i8 [M,C]

#define GLOAD_LDS16(g, l)                                                  \
  __builtin_amdgcn_global_load_lds(                                        \
      (const __attribute__((address_space(1))) void*)(g),                  \
      (__attribute__((address_space(3))) void*)(l), 16, 0, 0)

// ---------- mean(|W|) reduction ----------
__global__ void reduce_abs_kernel(const float* __restrict__ w, int n, double* __restrict__ part) {
  __shared__ double sm[256];
  double s = 0.0;
  for (int i = blockIdx.x * 256 + threadIdx.x; i < n; i += 256 * gridDim.x)
    s += (double)fabsf(w[i]);
  sm[threadIdx.x] = s;
  __syncthreads();
  for (int off = 128; off > 0; off >>= 1) {
    if (threadIdx.x < (unsigned)off) sm[threadIdx.x] += sm[threadIdx.x + off];
    __syncthreads();
  }
  if (threadIdx.x == 0) part[blockIdx.x] = sm[0];
}

__global__ void finalize_kernel(const double* __restrict__ pA, const double* __restrict__ pP,
                                double* __restrict__ means, double* __restrict__ tab,
                                const float* cq, const float* ck) {
  __shared__ double sm[256];
  int t = threadIdx.x;
  sm[t] = pA[t];
  __syncthreads();
  for (int off = 128; off > 0; off >>= 1) { if (t < off) sm[t] += sm[t + off]; __syncthreads(); }
  if (t == 0) means[0] = sm[0] / (double)((size_t)O3C * C);
  __syncthreads();
  sm[t] = pP[t];
  __syncthreads();
  for (int off = 128; off > 0; off >>= 1) { if (t < off) sm[t] += sm[t + off]; __syncthreads(); }
  if (t == 0) means[1] = sm[0] / (double)((size_t)C * C);
  double delta = (double)cq[0] * (double)ck[0] * 0.125;
  if (t < 129) tab[t] = exp((double)(t - 128) * delta);
  if (t < 16) tab[129 + t] = exp((double)t * delta);   // T2: exp(+j*delta)
}

// ---------- sign (binarize) to i8 {-1,0,1}, 8/thread ----------
__global__ void sign8_kernel(const float* __restrict__ x, signed char* __restrict__ out,
                             int n8, const float* alpha) {
  float a = alpha ? alpha[0] : 1.0f;
  signed char pos = (a > 0.0f) ? 1 : ((a < 0.0f) ? -1 : 0);
  signed char neg = (signed char)(-pos);
  int stride = 256 * gridDim.x;
  for (int i = blockIdx.x * 256 + threadIdx.x; i < n8; i += stride) {
    const float4* xp = (const float4*)(x + (size_t)i * 8);
    float4 u = xp[0], v = xp[1];
    float vals[8] = {u.x, u.y, u.z, u.w, v.x, v.y, v.z, v.w};
    char8v s;
#pragma unroll
    for (int j = 0; j < 8; ++j)
      s[j] = vals[j] > 0.0f ? pos : (vals[j] < 0.0f ? neg : (signed char)0);
    *(char8v*)(out + (size_t)i * 8) = s;
  }
}

// XCD-affinity decode
static __device__ inline bool xcd_decode(int lin, int nyb, int& x, int& y) {
  int k = lin & 7;
  int q = lin >> 3;
  int xi = q / nyb;
  y = q - xi * nyb;
  x = xi * 8 + k;
  return x < NXB;
}

// ---------- staged i8 GEMM, 2-phase dbuf with COUNTED vmcnt (T3+T4) ----------
static __device__ inline void stage_i8(const signed char* __restrict__ A,
                                       const signed char* __restrict__ Bmat,
                                       int i0, int o0, int k0,
                                       char* AsB, char* BsB) {
  int tid = threadIdx.x;
  int lane = tid & 63, w = tid >> 6;
#pragma unroll
  for (int c = 0; c < 4; ++c) {
    int ccb = w * 64 + c * 256;
    int cc = ccb + lane;
    int row = cc >> 3, cwl = cc & 7;
    int sc16 = (cwl ^ (row & 7)) * 16;   // pre-swizzled source
    GLOAD_LDS16(&A[(size_t)(i0 + row) * C + k0 + sc16], AsB + (size_t)ccb * 16);
    GLOAD_LDS16(&Bmat[(size_t)(o0 + row) * C + k0 + sc16], BsB + (size_t)ccb * 16);
  }
}

static __device__ inline void compute_i8(const signed char (*As)[128],
                                         const signed char (*Bs)[128],
                                         int4v acc[4][4]) {
  int lane = threadIdx.x & 63, w = threadIdx.x >> 6, wr = w >> 1, wc = w & 1;
#pragma unroll
  for (int kk = 0; kk < 2; ++kk) {
    int4v af[4], bf[4];
    int g = kk * 4 + (lane >> 4);
#pragma unroll
    for (int m = 0; m < 4; ++m) {
      int row = wr * 64 + m * 16 + (lane & 15);
      af[m] = *(const int4v*)&As[row][((g ^ (row & 7))) * 16];
    }
#pragma unroll
    for (int n2 = 0; n2 < 4; ++n2) {
      int row = wc * 64 + n2 * 16 + (lane & 15);
      bf[n2] = *(const int4v*)&Bs[row][((g ^ (row & 7))) * 16];
    }
    __builtin_amdgcn_s_setprio(1);
#pragma unroll
    for (int m = 0; m < 4; ++m)
#pragma unroll
      for (int n2 = 0; n2 < 4; ++n2)
        acc[m][n2] = __builtin_amdgcn_mfma_i32_16x16x64_i8(af[m], bf[n2], acc[m][n2], 0, 0, 0);
    __builtin_amdgcn_s_setprio(0);
  }
}

// Counted-vmcnt loop: prefetch t+1 stays IN FLIGHT across the barrier.
static __device__ inline void gemm_dbuf_i8(const signed char* __restrict__ A,
                                           const signed char* __restrict__ Bmat,
                                           int i0, int o0, char* smem, int4v acc[4][4]) {
  stage_i8(A, Bmat, i0, o0, 0, smem, smem + 16384);   // 8 loads/wave in flight
#pragma unroll
  for (int t = 0; t < 6; ++t) {
    const int cu = t & 1;
    if (t < 5) {
      stage_i8(A, Bmat, i0, o0, (t + 1) * 128,
               smem + (cu ^ 1) * 32768, smem + (cu ^ 1) * 32768 + 16384);
      asm volatile("s_waitcnt vmcnt(8)" ::: "memory");   // tile t done; t+1 in flight
    } else {
      asm volatile("s_waitcnt vmcnt(0)" ::: "memory");
    }
    __builtin_amdgcn_sched_barrier(0);
    __builtin_amdgcn_s_barrier();
    compute_i8((const signed char(*)[128])(smem + cu * 32768),
               (const signed char(*)[128])(smem + cu * 32768 + 16384), acc);
    __builtin_amdgcn_s_barrier();       // block done reading buf[cu] before overwrite
  }
}

// ---------- GEMM1: qkv = sign(x) @ sign(Wqkv)^T, i8 outputs ----------
__global__ __launch_bounds__(256) void gemm1_kernel(
    const signed char* __restrict__ Xs, const signed char* __restrict__ Wqs,
    const double* __restrict__ means,
    const float* cin, const float* cq, const float* ck,
    const float* cv1, const float* cv2, const float* cv3,
    const float* __restrict__ movq, const float* __restrict__ movk, const float* __restrict__ movv,
    signed char* __restrict__ Qs8, signed char* __restrict__ Ks8, signed char* __restrict__ Vt8) {
  int bx, by;
  if (!xcd_decode(blockIdx.x, O3C / 128, bx, by)) return;
  __shared__ __align__(16) char smem[65536];
  signed char* tile8 = (signed char*)smem;   // [128][TLD8], aliases staging after loop
  int4v acc[4][4] = {};
  int i0 = bx * 128, o0 = by * 128;
  gemm_dbuf_i8(Xs, Wqs, i0, o0, smem, acc);
  int tid = threadIdx.x;
  int lane = tid & 63, w = tid >> 6, wr = w >> 1, wc = w & 1;
  double cw_ = (double)cin[0] * means[0];
  float dq = cq[0], dk = ck[0];
  signed char sq8 = dq > 0.0f ? 1 : (dq < 0.0f ? -1 : 0);
  signed char sk8 = dk > 0.0f ? 1 : (dk < 0.0f ? -1 : 0);
  double aa1 = fabs((double)cv1[0]), aa2 = fabs((double)cv2[0]), aa3 = fabs((double)cv3[0]);
  int t = o0 / C;
  int rem0 = o0 - t * C;
  signed char sg8 = t == 0 ? sq8 : sk8;
  const float* mov = t == 0 ? movq : (t == 1 ? movk : movv);
#pragma unroll
  for (int m = 0; m < 4; ++m)
#pragma unroll
    for (int n2 = 0; n2 < 4; ++n2)
#pragma unroll
      for (int r = 0; r < 4; ++r) {
        int rowL = wr * 64 + m * 16 + (lane >> 4) * 4 + r;
        int colL = wc * 64 + n2 * 16 + (lane & 15);
        int rem = rem0 + colL;
        int h = rem >> 6, d = rem & 63;
        double g = (double)acc[m][n2][r] * cw_;
        if (t < 2) {
          double v = g + (double)mov[h * D + d];
          tile8[rowL * TLD8 + colL] = v > 0.0 ? sg8 : (v < 0.0 ? (signed char)(-sg8) : (signed char)0);
        } else {
          double rr = g + (double)mov[h * D + d];
          double b1 = rr > 0.0 ? aa1 : (rr < 0.0 ? -aa1 : 0.0);
          rr -= b1;
          double b2 = rr > 0.0 ? aa2 : (rr < 0.0 ? -aa2 : 0.0);
          rr -= b2;
          double b3 = rr > 0.0 ? aa3 : (rr < 0.0 ? -aa3 : 0.0);
          tile8[colL * TLD8 + rowL] = (signed char)(int)rint(4.0 * (b1 + b2 + b3)); // transposed
        }
      }
  __syncthreads();
  if (t < 2) {
    signed char* dst = t == 0 ? Qs8 : Ks8;
#pragma unroll
    for (int it = 0; it < 4; ++it) {
      int c = tid + it * 256;            // 1024 chunks of 16B
      int rowL = c >> 3, cch = c & 7;
      int gr = i0 + rowL;
      int b = gr / N, nn = gr - b * N;
      int rem = rem0 + cch * 16;
      int h = rem >> 6, d = rem & 63;
      *(uint4a*)&dst[((size_t)(b * H + h) * N + nn) * 64 + d] =
          *(const uint4a*)&tile8[rowL * TLD8 + cch * 16];
    }
  } else {
#pragma unroll
    for (int it = 0; it < 4; ++it) {
      int c = tid + it * 256;
      int colL = c >> 3, tch = c & 7;
      int rem = rem0 + colL;
      int h = rem >> 6, d = rem & 63;
      int gr0 = i0 + tch * 16;
      int b0 = gr0 / N, nn0 = gr0 - b0 * N;
      if (nn0 + 16 <= N) {
        *(uint4a*)&Vt8[((size_t)(b0 * H + h) * 64 + d) * VNP + nn0] =
            *(const uint4a*)&tile8[colL * TLD8 + tch * 16];
      } else {
#pragma unroll
        for (int j = 0; j < 16; ++j) {
          int gr = gr0 + j;
          int b = gr / N, nn = gr - b * N;
          Vt8[((size_t)(b * H + h) * 64 + d) * VNP + nn] = tile8[colL * TLD8 + tch * 16 + j];
        }
      }
    }
  }
}

// ---------- fused attention v6: all-i8, 4 waves/block, XCD-affine ----------
__global__ __launch_bounds__(256) void attn_kernel(
    const signed char* __restrict__ Qs8, const signed char* __restrict__ Ks8,
    const signed char* __restrict__ Vt8, const double* __restrict__ tab,
    const float* __restrict__ movatt,
    const float* ca1p, const float* ca2p, const float* ca3p, const float* cipp,
    signed char* __restrict__ Os) {
  __shared__ double Tl1[9];    // exp((16i-128)*delta): 9 entries, distinct banks
  __shared__ double Tl2[16];   // exp(j*delta): 16 entries = all 32 banks once
  __shared__ signed char Al8[4][16 * AL8];
  int i = blockIdx.x;
  int xcd = i & 7;
  int q = i >> 3;
  int rt = q % 13;
  int grp = q / 13;
  int tid = threadIdx.x;
  int w = tid >> 6, lane = tid & 63;
  int bh = (grp * 4 + w) * 8 + xcd;
  int b = bh / H, h = bh - b * H;
  int g = lane >> 4, q16 = lane & 15;
  if (tid < 9) Tl1[tid] = tab[16 * tid];
  if (tid >= 32 && tid < 48) Tl2[tid - 32] = tab[129 + (tid - 32)];
  // zero P-stripe pad cols 208..255 (own wave only)
  for (int ii = lane; ii < 192; ii += 64) {
    int row = ii / 12, cd = ii - row * 12;
    *(int*)&Al8[w][row * AL8 + 208 + cd * 4] = 0;
  }
  __syncthreads();
  double ca1 = (double)ca1p[0], ca2 = (double)ca2p[0], ca3 = (double)ca3p[0];
  double t1 = 0.5 * ca1, t2 = 0.5 * ca2, t3 = 0.5 * ca3;
  int q1 = (int)rint(4.0 * ca1), q2 = (int)rint(4.0 * ca2), q3 = (int)rint(4.0 * ca3);
  float cip = cipp[0];
  signed char cp = cip > 0.0f ? 1 : (cip < 0.0f ? -1 : 0);

  // --- Q fragment: one 16B i8 load covers K=64 ---
  int4v qf = {};
  int qrow = rt * 16 + q16;
  if (qrow < N) qf = *(const int4v*)&Qs8[((size_t)bh * N + qrow) * 64 + g * 16];
  // --- S = Q K^T: one i8 MFMA per column tile ---
  int4v sacc[13] = {};
#pragma unroll
  for (int ct = 0; ct < 13; ++ct) {
    int krow = ct * 16 + q16;
    int4v kf = {};
    if (krow < N) kf = *(const int4v*)&Ks8[((size_t)bh * N + krow) * 64 + g * 16];
    sacc[ct] = __builtin_amdgcn_mfma_i32_16x16x64_i8(qf, kf, sacc[ct], 0, 0, 0);
  }
  // --- softmax (f64, conflict-free split exp table) + bias + gsb -> integer P ---
#pragma unroll
  for (int r = 0; r < 4; ++r) {
    int rowg = rt * 16 + g * 4 + r;
    int rowc = rowg < N ? rowg : N - 1;
    const float* mrow = movatt + ((size_t)h * N + rowc) * N;
    int mx = -1000000;
#pragma unroll
    for (int ct = 0; ct < 13; ++ct) {
      int colc = ct * 16 + q16;
      if (colc < N) mx = max(mx, sacc[ct][r]);
    }
    mx = max(mx, __shfl_xor(mx, 1));
    mx = max(mx, __shfl_xor(mx, 2));
    mx = max(mx, __shfl_xor(mx, 4));
    mx = max(mx, __shfl_xor(mx, 8));
    double ev[13];
    double ssum = 0.0;
#pragma unroll
    for (int ct = 0; ct < 13; ++ct) {
      int colc = ct * 16 + q16;
      int idx = sacc[ct][r] - mx + 128;
      idx = idx > 128 ? 128 : idx;       // invalid lanes only
      double e = (colc < N) ? Tl1[idx >> 4] * Tl2[idx & 15] : 0.0;
      ev[ct] = e;
      ssum += e;
    }
    ssum += __shfl_xor(ssum, 1);
    ssum += __shfl_xor(ssum, 2);
    ssum += __shfl_xor(ssum, 4);
    ssum += __shfl_xor(ssum, 8);
    double rec = 1.0 / ssum;
#pragma unroll
    for (int ct = 0; ct < 13; ++ct) {
      int colc = ct * 16 + q16;
      int colb = colc < N ? colc : N - 1;
      double at = ev[ct] * rec + (double)mrow[colb];
      int p4 = 0;
      double rr = at;
      if (rr > t1) { p4 += q1; rr -= ca1; }
      if (rr > t2) { p4 += q2; rr -= ca2; }
      if (rr > t3) { p4 += q3; }
      Al8[w][(g * 4 + r) * AL8 + colc] = (signed char)((colc < N) ? p4 : 0);
    }
  }
  // per-wave stripe: no barrier needed (same wave writes & reads)
  // --- PV: i8 MFMA, K-range 256 (P pad = 0 -> V pad garbage harmless) ---
  int4v oacc[4] = {};
#pragma unroll
  for (int kt = 0; kt < 4; ++kt) {
    int4v af = *(const int4v*)&Al8[w][q16 * AL8 + kt * 64 + g * 16];
#pragma unroll
    for (int dt = 0; dt < 4; ++dt) {
      int4v bv = *(const int4v*)&Vt8[((size_t)bh * 64 + dt * 16 + q16) * VNP + kt * 64 + g * 16];
      oacc[dt] = __builtin_amdgcn_mfma_i32_16x16x64_i8(af, bv, oacc[dt], 0, 0, 0);
    }
  }
  // --- sign epilogue: acc = 16*sum(p*v), sign preserved ---
#pragma unroll
  for (int dt = 0; dt < 4; ++dt)
#pragma unroll
    for (int r = 0; r < 4; ++r) {
      int rowg = rt * 16 + g * 4 + r;
      if (rowg < N) {
        int d = dt * 16 + q16;
        int s = oacc[dt][r];
        Os[((size_t)(b * N + rowg)) * C + h * D + d] =
            s > 0 ? cp : (s < 0 ? (signed char)(-cp) : (signed char)0);
      }
    }
}

// ---------- GEMM2 ----------
__global__ __launch_bounds__(256) void gemm2_kernel(
    const signed char* __restrict__ Os, const signed char* __restrict__ Wps,
    const double* __restrict__ means, const float* cip, const float* __restrict__ proj_b,
    float* __restrict__ out) {
  int bx, by;
  if (!xcd_decode(blockIdx.x, C / 128, bx, by)) return;
  __shared__ __align__(16) char smem[65536];
  int4v acc[4][4] = {};
  int i0 = bx * 128, o0 = by * 128;
  gemm_dbuf_i8(Os, Wps, i0, o0, smem, acc);
  int lane = threadIdx.x & 63, w = threadIdx.x >> 6, wr = w >> 1, wc = w & 1;
  double cw_ = (double)cip[0] * means[1];
#pragma unroll
  for (int m = 0; m < 4; ++m)
#pragma unroll
    for (int n2 = 0; n2 < 4; ++n2)
#pragma unroll
      for (int r = 0; r < 4; ++r) {
        int row = i0 + wr * 64 + m * 16 + (lane >> 4) * 4 + r;
        int col = o0 + wc * 64 + n2 * 16 + (lane & 15);
        double v = (double)acc[m][n2][r] * cw_ + (double)proj_b[col];
        out[(size_t)row * C + col] = (float)v;
      }
}

extern "C" void kernel_launch(void* const* d_in, const int* in_sizes, int n_in,
                              void* d_out, int out_size, void* d_ws, size_t ws_size,
                              hipStream_t stream) {
  const float* x      = (const float*)d_in[0];
  const float* qkv_w  = (const float*)d_in[1];
  const float* proj_w = (const float*)d_in[2];
  const float* proj_b = (const float*)d_in[3];
  const float* movq   = (const float*)d_in[4];
  const float* movk   = (const float*)d_in[5];
  const float* movv   = (const float*)d_in[6];
  const float* movatt = (const float*)d_in[7];
  const float* c_inq  = (const float*)d_in[8];
  const float* c_q    = (const float*)d_in[9];
  const float* c_k    = (const float*)d_in[10];
  const float* c_v1   = (const float*)d_in[11];
  const float* c_v2   = (const float*)d_in[12];
  const float* c_v3   = (const float*)d_in[13];
  const float* c_a1   = (const float*)d_in[14];
  const float* c_a2   = (const float*)d_in[15];
  const float* c_a3   = (const float*)d_in[16];
  const float* c_inp  = (const float*)d_in[17];

  char* ws = (char*)d_ws;
  double* means = (double*)(ws + OFF_MEANS);
  double* tab   = (double*)(ws + OFF_TAB);
  double* partA = (double*)(ws + OFF_PARTA);
  double* partP = (double*)(ws + OFF_PARTP);
  signed char* Xs  = (signed char*)(ws + OFF_XS);
  signed char* Wqs = (signed char*)(ws + OFF_WQS);
  signed char* Wps = (signed char*)(ws + OFF_WPS);
  signed char* Qs8 = (signed char*)(ws + OFF_Q);
  signed char* Ks8 = (signed char*)(ws + OFF_K);
  signed char* Vt8 = (signed char*)(ws + OFF_VT);
  signed char* Os  = (signed char*)(ws + OFF_OS);

  reduce_abs_kernel<<<256, 256, 0, stream>>>(qkv_w, O3C * C, partA);
  reduce_abs_kernel<<<256, 256, 0, stream>>>(proj_w, C * C, partP);
  finalize_kernel<<<1, 256, 0, stream>>>(partA, partP, means, tab, c_q, c_k);
  sign8_kernel<<<2048, 256, 0, stream>>>(x, Xs, M * C / 8, c_inq);
  sign8_kernel<<<1024, 256, 0, stream>>>(qkv_w, Wqs, O3C * C / 8, nullptr);
  sign8_kernel<<<512, 256, 0, stream>>>(proj_w, Wps, C * C / 8, nullptr);
  gemm1_kernel<<<104 * (O3C / 128), 256, 0, stream>>>(
      Xs, Wqs, means, c_inq, c_q, c_k, c_v1, c_v2, c_v3, movq, movk, movv, Qs8, Ks8, Vt8);
  attn_kernel<<<8 * 13 * (BH / 32), 256, 0, stream>>>(Qs8, Ks8, Vt8, tab, movatt, c_a1, c_a2, c_a3, c_inp, Os);
  gemm2_kernel<<<104 * (C / 128), 256, 0, stream>>>(
      Os, Wps, means, c_inp, proj_b, (float*)d_out);
}

// Round 14
// 169.181 us; speedup vs baseline: 1.6198x; 1.0541x over previous
//
#include <hip/hip_runtime.h>
#include <hip/hip_bf16.h>

typedef __attribute__((ext_vector_type(8))) short short8;
typedef __attribute__((ext_vector_type(4))) float f32x4;
typedef __attribute__((ext_vector_type(4))) int int4v;
typedef __attribute__((ext_vector_type(8))) char char8v;
typedef __attribute__((ext_vector_type(4), aligned(4))) unsigned int uint4a;

static constexpr int B = 64, N = 198, C = 768, H = 12, D = 64;
static constexpr int M = B * N;          // 12672 = 99*128
static constexpr int BH = B * H;         // 768
static constexpr int O3C = 3 * C;        // 2304 = 18*128
static constexpr int NXB = 99;           // M/128
static constexpr int TLD8 = 144;         // gemm1 epilogue i8 tile stride
static constexpr int AL8 = 272;          // attn P-stripe i8 stride
static constexpr int VNP = 256;          // V^T i8 padded cols

// ---- workspace layout (bytes) ----
static constexpr size_t OFF_MEANS = 0;
static constexpr size_t OFF_TAB   = 256;   // 129 + 16 doubles
static constexpr size_t OFF_PARTA = 2048;
static constexpr size_t OFF_PARTP = 4096;
static constexpr size_t OFF_XS    = 8192;
static constexpr size_t SZ_XS     = (size_t)M * C;           // sign(x) i8
static constexpr size_t OFF_WQS   = OFF_XS + SZ_XS;
static constexpr size_t SZ_WQS    = (size_t)O3C * C;
static constexpr size_t OFF_WPS   = OFF_WQS + SZ_WQS;
static constexpr size_t SZ_WPS    = (size_t)C * C;
static constexpr size_t OFF_Q     = OFF_WPS + SZ_WPS;
static constexpr size_t SZ_QK8    = (size_t)BH * N * D;      // i8
static constexpr size_t OFF_K     = OFF_Q + SZ_QK8;
static constexpr size_t OFF_VT    = OFF_K + SZ_QK8;
static constexpr size_t SZ_VT8    = (size_t)BH * D * VNP;    // i8
static constexpr size_t OFF_OS    = OFF_VT + SZ_VT8;         // i8 [M,C]

#define GLOAD_LDS16(g, l)                                                  \
  __builtin_amdgcn_global_load_lds(                                        \
      (const __attribute__((address_space(1))) void*)(g),                  \
      (__attribute__((address_space(3))) void*)(l), 16, 0, 0)

// ---------- mean(|W|) reduction ----------
__global__ void reduce_abs_kernel(const float* __restrict__ w, int n, double* __restrict__ part) {
  __shared__ double sm[256];
  double s = 0.0;
  for (int i = blockIdx.x * 256 + threadIdx.x; i < n; i += 256 * gridDim.x)
    s += (double)fabsf(w[i]);
  sm[threadIdx.x] = s;
  __syncthreads();
  for (int off = 128; off > 0; off >>= 1) {
    if (threadIdx.x < (unsigned)off) sm[threadIdx.x] += sm[threadIdx.x + off];
    __syncthreads();
  }
  if (threadIdx.x == 0) part[blockIdx.x] = sm[0];
}

__global__ void finalize_kernel(const double* __restrict__ pA, const double* __restrict__ pP,
                                double* __restrict__ means, double* __restrict__ tab,
                                const float* cq, const float* ck) {
  __shared__ double sm[256];
  int t = threadIdx.x;
  sm[t] = pA[t];
  __syncthreads();
  for (int off = 128; off > 0; off >>= 1) { if (t < off) sm[t] += sm[t + off]; __syncthreads(); }
  if (t == 0) means[0] = sm[0] / (double)((size_t)O3C * C);
  __syncthreads();
  sm[t] = pP[t];
  __syncthreads();
  for (int off = 128; off > 0; off >>= 1) { if (t < off) sm[t] += sm[t + off]; __syncthreads(); }
  if (t == 0) means[1] = sm[0] / (double)((size_t)C * C);
  double delta = (double)cq[0] * (double)ck[0] * 0.125;
  if (t < 129) tab[t] = exp((double)(t - 128) * delta);
  if (t < 16) tab[129 + t] = exp((double)t * delta);   // T2: exp(+j*delta)
}

// ---------- sign (binarize) to i8 {-1,0,1}, 8/thread ----------
__global__ void sign8_kernel(const float* __restrict__ x, signed char* __restrict__ out,
                             int n8, const float* alpha) {
  float a = alpha ? alpha[0] : 1.0f;
  signed char pos = (a > 0.0f) ? 1 : ((a < 0.0f) ? -1 : 0);
  signed char neg = (signed char)(-pos);
  int stride = 256 * gridDim.x;
  for (int i = blockIdx.x * 256 + threadIdx.x; i < n8; i += stride) {
    const float4* xp = (const float4*)(x + (size_t)i * 8);
    float4 u = xp[0], v = xp[1];
    float vals[8] = {u.x, u.y, u.z, u.w, v.x, v.y, v.z, v.w};
    char8v s;
#pragma unroll
    for (int j = 0; j < 8; ++j)
      s[j] = vals[j] > 0.0f ? pos : (vals[j] < 0.0f ? neg : (signed char)0);
    *(char8v*)(out + (size_t)i * 8) = s;
  }
}

// XCD-affinity decode
static __device__ inline bool xcd_decode(int lin, int nyb, int& x, int& y) {
  int k = lin & 7;
  int q = lin >> 3;
  int xi = q / nyb;
  y = q - xi * nyb;
  x = xi * 8 + k;
  return x < NXB;
}

// ---------- staged i8 GEMM, BK=64, 2-phase dbuf, counted vmcnt ----------
// Tiles 128x64 i8 = 8KB each; dbuf A+B = 32KB -> ~5 blocks/CU.
// Per-row chunk swizzle pi(c) = c ^ ((row>>1)&3): LDS linear dest, pre-swizzled
// global source, same XOR on read. Bank check: rows r,r+8 2-way (free), r+4 disjoint.
static __device__ inline void stage_i8(const signed char* __restrict__ A,
                                       const signed char* __restrict__ Bmat,
                                       int i0, int o0, int k0,
                                       char* AsB, char* BsB) {
  int tid = threadIdx.x;
  int lane = tid & 63, w = tid >> 6;
#pragma unroll
  for (int c = 0; c < 2; ++c) {
    int ccb = w * 64 + c * 256;          // wave-uniform 16B-chunk base (512 chunks/matrix)
    int cc = ccb + lane;
    int row = cc >> 2, cwl = cc & 3;
    int sc16 = (cwl ^ ((row >> 1) & 3)) * 16;
    GLOAD_LDS16(&A[(size_t)(i0 + row) * C + k0 + sc16], AsB + (size_t)ccb * 16);
    GLOAD_LDS16(&Bmat[(size_t)(o0 + row) * C + k0 + sc16], BsB + (size_t)ccb * 16);
  }
}

static __device__ inline void compute_i8(const signed char (*As)[64],
                                         const signed char (*Bs)[64],
                                         int4v acc[4][4]) {
  int lane = threadIdx.x & 63, w = threadIdx.x >> 6, wr = w >> 1, wc = w & 1;
  int g = lane >> 4;                     // k-chunk 0..3
  int4v af[4], bf[4];
#pragma unroll
  for (int m = 0; m < 4; ++m) {
    int row = wr * 64 + m * 16 + (lane & 15);
    af[m] = *(const int4v*)&As[row][((g ^ ((row >> 1) & 3))) * 16];
  }
#pragma unroll
  for (int n2 = 0; n2 < 4; ++n2) {
    int row = wc * 64 + n2 * 16 + (lane & 15);
    bf[n2] = *(const int4v*)&Bs[row][((g ^ ((row >> 1) & 3))) * 16];
  }
  __builtin_amdgcn_s_setprio(1);
#pragma unroll
  for (int m = 0; m < 4; ++m)
#pragma unroll
    for (int n2 = 0; n2 < 4; ++n2)
      acc[m][n2] = __builtin_amdgcn_mfma_i32_16x16x64_i8(af[m], bf[n2], acc[m][n2], 0, 0, 0);
  __builtin_amdgcn_s_setprio(0);
}

// smem layout: A0@0, B0@8K, A1@16K, B1@24K (32KB total).
static __device__ inline void gemm_dbuf_i8(const signed char* __restrict__ A,
                                           const signed char* __restrict__ Bmat,
                                           int i0, int o0, char* smem, int4v acc[4][4]) {
  stage_i8(A, Bmat, i0, o0, 0, smem, smem + 8192);   // 4 loads/wave in flight
#pragma unroll
  for (int t = 0; t < 12; ++t) {
    const int cu = t & 1;
    if (t < 11) {
      stage_i8(A, Bmat, i0, o0, (t + 1) * 64,
               smem + (cu ^ 1) * 16384, smem + (cu ^ 1) * 16384 + 8192);
      asm volatile("s_waitcnt vmcnt(4)" ::: "memory");   // tile t done; t+1 in flight
    } else {
      asm volatile("s_waitcnt vmcnt(0)" ::: "memory");
    }
    __builtin_amdgcn_sched_barrier(0);
    __builtin_amdgcn_s_barrier();
    compute_i8((const signed char(*)[64])(smem + cu * 16384),
               (const signed char(*)[64])(smem + cu * 16384 + 8192), acc);
    __builtin_amdgcn_s_barrier();       // block done reading buf[cu] before overwrite
  }
}

// ---------- GEMM1: qkv = sign(x) @ sign(Wqkv)^T, i8 outputs ----------
__global__ __launch_bounds__(256) void gemm1_kernel(
    const signed char* __restrict__ Xs, const signed char* __restrict__ Wqs,
    const double* __restrict__ means,
    const float* cin, const float* cq, const float* ck,
    const float* cv1, const float* cv2, const float* cv3,
    const float* __restrict__ movq, const float* __restrict__ movk, const float* __restrict__ movv,
    signed char* __restrict__ Qs8, signed char* __restrict__ Ks8, signed char* __restrict__ Vt8) {
  int bx, by;
  if (!xcd_decode(blockIdx.x, O3C / 128, bx, by)) return;
  __shared__ __align__(16) char smem[32768];
  signed char* tile8 = (signed char*)smem;   // [128][TLD8] = 18432 B, aliases staging
  int4v acc[4][4] = {};
  int i0 = bx * 128, o0 = by * 128;
  gemm_dbuf_i8(Xs, Wqs, i0, o0, smem, acc);
  int tid = threadIdx.x;
  int lane = tid & 63, w = tid >> 6, wr = w >> 1, wc = w & 1;
  double cw_ = (double)cin[0] * means[0];
  float dq = cq[0], dk = ck[0];
  signed char sq8 = dq > 0.0f ? 1 : (dq < 0.0f ? -1 : 0);
  signed char sk8 = dk > 0.0f ? 1 : (dk < 0.0f ? -1 : 0);
  double aa1 = fabs((double)cv1[0]), aa2 = fabs((double)cv2[0]), aa3 = fabs((double)cv3[0]);
  int t = o0 / C;
  int rem0 = o0 - t * C;
  signed char sg8 = t == 0 ? sq8 : sk8;
  const float* mov = t == 0 ? movq : (t == 1 ? movk : movv);
  __syncthreads();                        // staging reads done before tile8 overwrite
#pragma unroll
  for (int m = 0; m < 4; ++m)
#pragma unroll
    for (int n2 = 0; n2 < 4; ++n2)
#pragma unroll
      for (int r = 0; r < 4; ++r) {
        int rowL = wr * 64 + m * 16 + (lane >> 4) * 4 + r;
        int colL = wc * 64 + n2 * 16 + (lane & 15);
        int rem = rem0 + colL;
        int h = rem >> 6, d = rem & 63;
        double g = (double)acc[m][n2][r] * cw_;
        if (t < 2) {
          double v = g + (double)mov[h * D + d];
          tile8[rowL * TLD8 + colL] = v > 0.0 ? sg8 : (v < 0.0 ? (signed char)(-sg8) : (signed char)0);
        } else {
          double rr = g + (double)mov[h * D + d];
          double b1 = rr > 0.0 ? aa1 : (rr < 0.0 ? -aa1 : 0.0);
          rr -= b1;
          double b2 = rr > 0.0 ? aa2 : (rr < 0.0 ? -aa2 : 0.0);
          rr -= b2;
          double b3 = rr > 0.0 ? aa3 : (rr < 0.0 ? -aa3 : 0.0);
          tile8[colL * TLD8 + rowL] = (signed char)(int)rint(4.0 * (b1 + b2 + b3)); // transposed
        }
      }
  __syncthreads();
  if (t < 2) {
    signed char* dst = t == 0 ? Qs8 : Ks8;
#pragma unroll
    for (int it = 0; it < 4; ++it) {
      int c = tid + it * 256;            // 1024 chunks of 16B
      int rowL = c >> 3, cch = c & 7;
      int gr = i0 + rowL;
      int b = gr / N, nn = gr - b * N;
      int rem = rem0 + cch * 16;
      int h = rem >> 6, d = rem & 63;
      *(uint4a*)&dst[((size_t)(b * H + h) * N + nn) * 64 + d] =
          *(const uint4a*)&tile8[rowL * TLD8 + cch * 16];
    }
  } else {
#pragma unroll
    for (int it = 0; it < 4; ++it) {
      int c = tid + it * 256;
      int colL = c >> 3, tch = c & 7;
      int rem = rem0 + colL;
      int h = rem >> 6, d = rem & 63;
      int gr0 = i0 + tch * 16;
      int b0 = gr0 / N, nn0 = gr0 - b0 * N;
      if (nn0 + 16 <= N) {
        *(uint4a*)&Vt8[((size_t)(b0 * H + h) * 64 + d) * VNP + nn0] =
            *(const uint4a*)&tile8[colL * TLD8 + tch * 16];
      } else {
#pragma unroll
        for (int j = 0; j < 16; ++j) {
          int gr = gr0 + j;
          int b = gr / N, nn = gr - b * N;
          Vt8[((size_t)(b * H + h) * 64 + d) * VNP + nn] = tile8[colL * TLD8 + tch * 16 + j];
        }
      }
    }
  }
}

// ---------- fused attention v6: all-i8, 4 waves/block, XCD-affine ----------
__global__ __launch_bounds__(256) void attn_kernel(
    const signed char* __restrict__ Qs8, const signed char* __restrict__ Ks8,
    const signed char* __restrict__ Vt8, const double* __restrict__ tab,
    const float* __restrict__ movatt,
    const float* ca1p, const float* ca2p, const float* ca3p, const float* cipp,
    signed char* __restrict__ Os) {
  __shared__ double Tl1[9];    // exp((16i-128)*delta)
  __shared__ double Tl2[16];   // exp(j*delta)
  __shared__ signed char Al8[4][16 * AL8];
  int i = blockIdx.x;
  int xcd = i & 7;
  int q = i >> 3;
  int rt = q % 13;
  int grp = q / 13;
  int tid = threadIdx.x;
  int w = tid >> 6, lane = tid & 63;
  int bh = (grp * 4 + w) * 8 + xcd;
  int b = bh / H, h = bh - b * H;
  int g = lane >> 4, q16 = lane & 15;
  if (tid < 9) Tl1[tid] = tab[16 * tid];
  if (tid >= 32 && tid < 48) Tl2[tid - 32] = tab[129 + (tid - 32)];
  for (int ii = lane; ii < 192; ii += 64) {
    int row = ii / 12, cd = ii - row * 12;
    *(int*)&Al8[w][row * AL8 + 208 + cd * 4] = 0;
  }
  __syncthreads();
  double ca1 = (double)ca1p[0], ca2 = (double)ca2p[0], ca3 = (double)ca3p[0];
  double t1 = 0.5 * ca1, t2 = 0.5 * ca2, t3 = 0.5 * ca3;
  int q1 = (int)rint(4.0 * ca1), q2 = (int)rint(4.0 * ca2), q3 = (int)rint(4.0 * ca3);
  float cip = cipp[0];
  signed char cp = cip > 0.0f ? 1 : (cip < 0.0f ? -1 : 0);

  int4v qf = {};
  int qrow = rt * 16 + q16;
  if (qrow < N) qf = *(const int4v*)&Qs8[((size_t)bh * N + qrow) * 64 + g * 16];
  int4v sacc[13] = {};
#pragma unroll
  for (int ct = 0; ct < 13; ++ct) {
    int krow = ct * 16 + q16;
    int4v kf = {};
    if (krow < N) kf = *(const int4v*)&Ks8[((size_t)bh * N + krow) * 64 + g * 16];
    sacc[ct] = __builtin_amdgcn_mfma_i32_16x16x64_i8(qf, kf, sacc[ct], 0, 0, 0);
  }
#pragma unroll
  for (int r = 0; r < 4; ++r) {
    int rowg = rt * 16 + g * 4 + r;
    int rowc = rowg < N ? rowg : N - 1;
    const float* mrow = movatt + ((size_t)h * N + rowc) * N;
    int mx = -1000000;
#pragma unroll
    for (int ct = 0; ct < 13; ++ct) {
      int colc = ct * 16 + q16;
      if (colc < N) mx = max(mx, sacc[ct][r]);
    }
    mx = max(mx, __shfl_xor(mx, 1));
    mx = max(mx, __shfl_xor(mx, 2));
    mx = max(mx, __shfl_xor(mx, 4));
    mx = max(mx, __shfl_xor(mx, 8));
    double ev[13];
    double ssum = 0.0;
#pragma unroll
    for (int ct = 0; ct < 13; ++ct) {
      int colc = ct * 16 + q16;
      int idx = sacc[ct][r] - mx + 128;
      idx = idx > 128 ? 128 : idx;
      double e = (colc < N) ? Tl1[idx >> 4] * Tl2[idx & 15] : 0.0;
      ev[ct] = e;
      ssum += e;
    }
    ssum += __shfl_xor(ssum, 1);
    ssum += __shfl_xor(ssum, 2);
    ssum += __shfl_xor(ssum, 4);
    ssum += __shfl_xor(ssum, 8);
    double rec = 1.0 / ssum;
#pragma unroll
    for (int ct = 0; ct < 13; ++ct) {
      int colc = ct * 16 + q16;
      int colb = colc < N ? colc : N - 1;
      double at = ev[ct] * rec + (double)mrow[colb];
      int p4 = 0;
      double rr = at;
      if (rr > t1) { p4 += q1; rr -= ca1; }
      if (rr > t2) { p4 += q2; rr -= ca2; }
      if (rr > t3) { p4 += q3; }
      Al8[w][(g * 4 + r) * AL8 + colc] = (signed char)((colc < N) ? p4 : 0);
    }
  }
  int4v oacc[4] = {};
#pragma unroll
  for (int kt = 0; kt < 4; ++kt) {
    int4v af = *(const int4v*)&Al8[w][q16 * AL8 + kt * 64 + g * 16];
#pragma unroll
    for (int dt = 0; dt < 4; ++dt) {
      int4v bv = *(const int4v*)&Vt8[((size_t)bh * 64 + dt * 16 + q16) * VNP + kt * 64 + g * 16];
      oacc[dt] = __builtin_amdgcn_mfma_i32_16x16x64_i8(af, bv, oacc[dt], 0, 0, 0);
    }
  }
#pragma unroll
  for (int dt = 0; dt < 4; ++dt)
#pragma unroll
    for (int r = 0; r < 4; ++r) {
      int rowg = rt * 16 + g * 4 + r;
      if (rowg < N) {
        int d = dt * 16 + q16;
        int s = oacc[dt][r];
        Os[((size_t)(b * N + rowg)) * C + h * D + d] =
            s > 0 ? cp : (s < 0 ? (signed char)(-cp) : (signed char)0);
      }
    }
}

// ---------- GEMM2 ----------
__global__ __launch_bounds__(256) void gemm2_kernel(
    const signed char* __restrict__ Os, const signed char* __restrict__ Wps,
    const double* __restrict__ means, const float* cip, const float* __restrict__ proj_b,
    float* __restrict__ out) {
  int bx, by;
  if (!xcd_decode(blockIdx.x, C / 128, bx, by)) return;
  __shared__ __align__(16) char smem[32768];
  int4v acc[4][4] = {};
  int i0 = bx * 128, o0 = by * 128;
  gemm_dbuf_i8(Os, Wps, i0, o0, smem, acc);
  int lane = threadIdx.x & 63, w = threadIdx.x >> 6, wr = w >> 1, wc = w & 1;
  double cw_ = (double)cip[0] * means[1];
#pragma unroll
  for (int m = 0; m < 4; ++m)
#pragma unroll
    for (int n2 = 0; n2 < 4; ++n2)
#pragma unroll
      for (int r = 0; r < 4; ++r) {
        int row = i0 + wr * 64 + m * 16 + (lane >> 4) * 4 + r;
        int col = o0 + wc * 64 + n2 * 16 + (lane & 15);
        double v = (double)acc[m][n2][r] * cw_ + (double)proj_b[col];
        out[(size_t)row * C + col] = (float)v;
      }
}

extern "C" void kernel_launch(void* const* d_in, const int* in_sizes, int n_in,
                              void* d_out, int out_size, void* d_ws, size_t ws_size,
                              hipStream_t stream) {
  const float* x      = (const float*)d_in[0];
  const float* qkv_w  = (const float*)d_in[1];
  const float* proj_w = (const float*)d_in[2];
  const float* proj_b = (const float*)d_in[3];
  const float* movq   = (const float*)d_in[4];
  const float* movk   = (const float*)d_in[5];
  const float* movv   = (const float*)d_in[6];
  const float* movatt = (const float*)d_in[7];
  const float* c_inq  = (const float*)d_in[8];
  const float* c_q    = (const float*)d_in[9];
  const float* c_k    = (const float*)d_in[10];
  const float* c_v1   = (const float*)d_in[11];
  const float* c_v2   = (const float*)d_in[12];
  const float* c_v3   = (const float*)d_in[13];
  const float* c_a1   = (const float*)d_in[14];
  const float* c_a2   = (const float*)d_in[15];
  const float* c_a3   = (const float*)d_in[16];
  const float* c_inp  = (const float*)d_in[17];

  char* ws = (char*)d_ws;
  double* means = (double*)(ws + OFF_MEANS);
  double* tab   = (double*)(ws + OFF_TAB);
  double* partA = (double*)(ws + OFF_PARTA);
  double* partP = (double*)(ws + OFF_PARTP);
  signed char* Xs  = (signed char*)(ws + OFF_XS);
  signed char* Wqs = (signed char*)(ws + OFF_WQS);
  signed char* Wps = (signed char*)(ws + OFF_WPS);
  signed char* Qs8 = (signed char*)(ws + OFF_Q);
  signed char* Ks8 = (signed char*)(ws + OFF_K);
  signed char* Vt8 = (signed char*)(ws + OFF_VT);
  signed char* Os  = (signed char*)(ws + OFF_OS);

  reduce_abs_kernel<<<256, 256, 0, stream>>>(qkv_w, O3C * C, partA);
  reduce_abs_kernel<<<256, 256, 0, stream>>>(proj_w, C * C, partP);
  finalize_kernel<<<1, 256, 0, stream>>>(partA, partP, means, tab, c_q, c_k);
  sign8_kernel<<<2048, 256, 0, stream>>>(x, Xs, M * C / 8, c_inq);
  sign8_kernel<<<1024, 256, 0, stream>>>(qkv_w, Wqs, O3C * C / 8, nullptr);
  sign8_kernel<<<512, 256, 0, stream>>>(proj_w, Wps, C * C / 8, nullptr);
  gemm1_kernel<<<104 * (O3C / 128), 256, 0, stream>>>(
      Xs, Wqs, means, c_inq, c_q, c_k, c_v1, c_v2, c_v3, movq, movk, movv, Qs8, Ks8, Vt8);
  attn_kernel<<<8 * 13 * (BH / 32), 256, 0, stream>>>(Qs8, Ks8, Vt8, tab, movatt, c_a1, c_a2, c_a3, c_inp, Os);
  gemm2_kernel<<<104 * (C / 128), 256, 0, stream>>>(
      Os, Wps, means, c_inp, proj_b, (float*)d_out);
}

// Round 15
// 161.350 us; speedup vs baseline: 1.6984x; 1.0485x over previous
//
#include <hip/hip_runtime.h>
#include <hip/hip_bf16.h>

typedef __attribute__((ext_vector_type(8))) short short8;
typedef __attribute__((ext_vector_type(4))) float f32x4;
typedef __attribute__((ext_vector_type(4))) int int4v;
typedef __attribute__((ext_vector_type(8))) char char8v;
typedef __attribute__((ext_vector_type(4), aligned(4))) unsigned int uint4a;

static constexpr int B = 64, N = 198, C = 768, H = 12, D = 64;
static constexpr int M = B * N;          // 12672 = 99*128
static constexpr int BH = B * H;         // 768
static constexpr int O3C = 3 * C;        // 2304 = 18*128
static constexpr int NXB = 99;           // M/128
static constexpr int TLD8 = 144;         // gemm1 epilogue i8 tile stride
static constexpr int AL8 = 272;          // attn P-stripe i8 stride
static constexpr int VNP = 256;          // V^T i8 padded cols

// ---- workspace layout (bytes) ----
static constexpr size_t OFF_MEANS = 0;
static constexpr size_t OFF_TAB   = 256;   // 129 + 16 doubles
static constexpr size_t OFF_PARTA = 2048;
static constexpr size_t OFF_PARTP = 4096;
static constexpr size_t OFF_XS    = 8192;
static constexpr size_t SZ_XS     = (size_t)M * C;           // sign(x) i8
static constexpr size_t OFF_WQS   = OFF_XS + SZ_XS;
static constexpr size_t SZ_WQS    = (size_t)O3C * C;
static constexpr size_t OFF_WPS   = OFF_WQS + SZ_WQS;
static constexpr size_t SZ_WPS    = (size_t)C * C;
static constexpr size_t OFF_Q     = OFF_WPS + SZ_WPS;
static constexpr size_t SZ_QK8    = (size_t)BH * N * D;      // i8
static constexpr size_t OFF_K     = OFF_Q + SZ_QK8;
static constexpr size_t OFF_VT    = OFF_K + SZ_QK8;
static constexpr size_t SZ_VT8    = (size_t)BH * D * VNP;    // i8
static constexpr size_t OFF_OS    = OFF_VT + SZ_VT8;         // i8 [M,C]

#define GLOAD_LDS16(g, l)                                                  \
  __builtin_amdgcn_global_load_lds(                                        \
      (const __attribute__((address_space(1))) void*)(g),                  \
      (__attribute__((address_space(3))) void*)(l), 16, 0, 0)

// ---------- merged mean(|W|) reduction: blocks 0..255 qkv_w, 256..511 proj_w ----------
__global__ void reduce_abs2_kernel(const float* __restrict__ qw, int nq,
                                   const float* __restrict__ pw, int np,
                                   double* __restrict__ partA, double* __restrict__ partP) {
  __shared__ double sm[256];
  const float* src;
  int n, b;
  double* dst;
  if (blockIdx.x < 256) { src = qw; n = nq; dst = partA; b = blockIdx.x; }
  else                  { src = pw; n = np; dst = partP; b = blockIdx.x - 256; }
  double s = 0.0;
  for (int i = b * 256 + threadIdx.x; i < n; i += 256 * 256)
    s += (double)fabsf(src[i]);
  sm[threadIdx.x] = s;
  __syncthreads();
  for (int off = 128; off > 0; off >>= 1) {
    if (threadIdx.x < (unsigned)off) sm[threadIdx.x] += sm[threadIdx.x + off];
    __syncthreads();
  }
  if (threadIdx.x == 0) dst[b] = sm[0];
}

__global__ void finalize_kernel(const double* __restrict__ pA, const double* __restrict__ pP,
                                double* __restrict__ means, double* __restrict__ tab,
                                const float* cq, const float* ck) {
  __shared__ double sm[256];
  int t = threadIdx.x;
  sm[t] = pA[t];
  __syncthreads();
  for (int off = 128; off > 0; off >>= 1) { if (t < off) sm[t] += sm[t + off]; __syncthreads(); }
  if (t == 0) means[0] = sm[0] / (double)((size_t)O3C * C);
  __syncthreads();
  sm[t] = pP[t];
  __syncthreads();
  for (int off = 128; off > 0; off >>= 1) { if (t < off) sm[t] += sm[t + off]; __syncthreads(); }
  if (t == 0) means[1] = sm[0] / (double)((size_t)C * C);
  double delta = (double)cq[0] * (double)ck[0] * 0.125;
  if (t < 129) tab[t] = exp((double)(t - 128) * delta);
  if (t < 16) tab[129 + t] = exp((double)t * delta);   // T2: exp(+j*delta)
}

// ---------- merged sign kernel: x | qkv_w | proj_w in one dispatch ----------
__global__ void sign8_all_kernel(const float* __restrict__ x, signed char* __restrict__ Xs,
                                 const float* __restrict__ qw, signed char* __restrict__ Wq,
                                 const float* __restrict__ pw, signed char* __restrict__ Wp,
                                 int nx8, int nq8, int np8, const float* alpha) {
  float a = alpha[0];
  signed char posx = (a > 0.0f) ? 1 : ((a < 0.0f) ? -1 : 0);
  int total = nx8 + nq8 + np8;
  int stride = 256 * gridDim.x;
  for (int i = blockIdx.x * 256 + threadIdx.x; i < total; i += stride) {
    const float* src;
    signed char* dst;
    int j;
    signed char pos;
    if (i < nx8) { src = x; dst = Xs; j = i; pos = posx; }
    else if (i < nx8 + nq8) { src = qw; dst = Wq; j = i - nx8; pos = 1; }
    else { src = pw; dst = Wp; j = i - nx8 - nq8; pos = 1; }
    signed char neg = (signed char)(-pos);
    const float4* xp = (const float4*)(src + (size_t)j * 8);
    float4 u = xp[0], v = xp[1];
    float vals[8] = {u.x, u.y, u.z, u.w, v.x, v.y, v.z, v.w};
    char8v s;
#pragma unroll
    for (int k = 0; k < 8; ++k)
      s[k] = vals[k] > 0.0f ? pos : (vals[k] < 0.0f ? neg : (signed char)0);
    *(char8v*)(dst + (size_t)j * 8) = s;
  }
}

// XCD-affinity decode
static __device__ inline bool xcd_decode(int lin, int nyb, int& x, int& y) {
  int k = lin & 7;
  int q = lin >> 3;
  int xi = q / nyb;
  y = q - xi * nyb;
  x = xi * 8 + k;
  return x < NXB;
}

// ---------- staged i8 GEMM, BK=64, single-barrier 2-phase (T3 minimum recipe) ----------
static __device__ inline void stage_i8(const signed char* __restrict__ A,
                                       const signed char* __restrict__ Bmat,
                                       int i0, int o0, int k0,
                                       char* AsB, char* BsB) {
  int tid = threadIdx.x;
  int lane = tid & 63, w = tid >> 6;
#pragma unroll
  for (int c = 0; c < 2; ++c) {
    int ccb = w * 64 + c * 256;          // wave-uniform 16B-chunk base
    int cc = ccb + lane;
    int row = cc >> 2, cwl = cc & 3;
    int sc16 = (cwl ^ ((row >> 1) & 3)) * 16;   // pre-swizzled source
    GLOAD_LDS16(&A[(size_t)(i0 + row) * C + k0 + sc16], AsB + (size_t)ccb * 16);
    GLOAD_LDS16(&Bmat[(size_t)(o0 + row) * C + k0 + sc16], BsB + (size_t)ccb * 16);
  }
}

static __device__ inline void compute_i8(const signed char (*As)[64],
                                         const signed char (*Bs)[64],
                                         int4v acc[4][4]) {
  int lane = threadIdx.x & 63, w = threadIdx.x >> 6, wr = w >> 1, wc = w & 1;
  int g = lane >> 4;                     // k-chunk 0..3
  int4v af[4], bf[4];
#pragma unroll
  for (int m = 0; m < 4; ++m) {
    int row = wr * 64 + m * 16 + (lane & 15);
    af[m] = *(const int4v*)&As[row][((g ^ ((row >> 1) & 3))) * 16];
  }
#pragma unroll
  for (int n2 = 0; n2 < 4; ++n2) {
    int row = wc * 64 + n2 * 16 + (lane & 15);
    bf[n2] = *(const int4v*)&Bs[row][((g ^ ((row >> 1) & 3))) * 16];
  }
  __builtin_amdgcn_s_setprio(1);
#pragma unroll
  for (int m = 0; m < 4; ++m)
#pragma unroll
    for (int n2 = 0; n2 < 4; ++n2)
      acc[m][n2] = __builtin_amdgcn_mfma_i32_16x16x64_i8(af[m], bf[n2], acc[m][n2], 0, 0, 0);
  __builtin_amdgcn_s_setprio(0);
}

// Single-barrier loop: STAGE(t+1) issued BEFORE compute(t) (loads fly under
// MFMA), then vmcnt(0)+barrier once per tile. WAR on buf[(t+1)&1] is protected
// by the end-of-(t-1) barrier (waves pass it only after consuming their reads).
static __device__ inline void gemm_dbuf_i8(const signed char* __restrict__ A,
                                           const signed char* __restrict__ Bmat,
                                           int i0, int o0, char* smem, int4v acc[4][4]) {
  stage_i8(A, Bmat, i0, o0, 0, smem, smem + 8192);
  asm volatile("s_waitcnt vmcnt(0)" ::: "memory");
  __builtin_amdgcn_sched_barrier(0);
  __builtin_amdgcn_s_barrier();
#pragma unroll
  for (int t = 0; t < 12; ++t) {
    const int cu = t & 1;
    if (t < 11)
      stage_i8(A, Bmat, i0, o0, (t + 1) * 64,
               smem + (cu ^ 1) * 16384, smem + (cu ^ 1) * 16384 + 8192);
    compute_i8((const signed char(*)[64])(smem + cu * 16384),
               (const signed char(*)[64])(smem + cu * 16384 + 8192), acc);
    if (t < 11) {
      asm volatile("s_waitcnt vmcnt(0)" ::: "memory");
      __builtin_amdgcn_sched_barrier(0);
      __builtin_amdgcn_s_barrier();
    }
  }
}

// ---------- GEMM1: qkv = sign(x) @ sign(Wqkv)^T, i8 outputs ----------
__global__ __launch_bounds__(256) void gemm1_kernel(
    const signed char* __restrict__ Xs, const signed char* __restrict__ Wqs,
    const double* __restrict__ means,
    const float* cin, const float* cq, const float* ck,
    const float* cv1, const float* cv2, const float* cv3,
    const float* __restrict__ movq, const float* __restrict__ movk, const float* __restrict__ movv,
    signed char* __restrict__ Qs8, signed char* __restrict__ Ks8, signed char* __restrict__ Vt8) {
  int bx, by;
  if (!xcd_decode(blockIdx.x, O3C / 128, bx, by)) return;
  __shared__ __align__(16) char smem[32768];
  signed char* tile8 = (signed char*)smem;   // [128][TLD8] = 18432 B, aliases staging
  int4v acc[4][4] = {};
  int i0 = bx * 128, o0 = by * 128;
  gemm_dbuf_i8(Xs, Wqs, i0, o0, smem, acc);
  int tid = threadIdx.x;
  int lane = tid & 63, w = tid >> 6, wr = w >> 1, wc = w & 1;
  double cw_ = (double)cin[0] * means[0];
  float dq = cq[0], dk = ck[0];
  signed char sq8 = dq > 0.0f ? 1 : (dq < 0.0f ? -1 : 0);
  signed char sk8 = dk > 0.0f ? 1 : (dk < 0.0f ? -1 : 0);
  double aa1 = fabs((double)cv1[0]), aa2 = fabs((double)cv2[0]), aa3 = fabs((double)cv3[0]);
  int t = o0 / C;
  int rem0 = o0 - t * C;
  signed char sg8 = t == 0 ? sq8 : sk8;
  const float* mov = t == 0 ? movq : (t == 1 ? movk : movv);
  __syncthreads();                        // staging reads done before tile8 overwrite
#pragma unroll
  for (int m = 0; m < 4; ++m)
#pragma unroll
    for (int n2 = 0; n2 < 4; ++n2)
#pragma unroll
      for (int r = 0; r < 4; ++r) {
        int rowL = wr * 64 + m * 16 + (lane >> 4) * 4 + r;
        int colL = wc * 64 + n2 * 16 + (lane & 15);
        int rem = rem0 + colL;
        int h = rem >> 6, d = rem & 63;
        double g = (double)acc[m][n2][r] * cw_;
        if (t < 2) {
          double v = g + (double)mov[h * D + d];
          tile8[rowL * TLD8 + colL] = v > 0.0 ? sg8 : (v < 0.0 ? (signed char)(-sg8) : (signed char)0);
        } else {
          double rr = g + (double)mov[h * D + d];
          double b1 = rr > 0.0 ? aa1 : (rr < 0.0 ? -aa1 : 0.0);
          rr -= b1;
          double b2 = rr > 0.0 ? aa2 : (rr < 0.0 ? -aa2 : 0.0);
          rr -= b2;
          double b3 = rr > 0.0 ? aa3 : (rr < 0.0 ? -aa3 : 0.0);
          tile8[colL * TLD8 + rowL] = (signed char)(int)rint(4.0 * (b1 + b2 + b3)); // transposed
        }
      }
  __syncthreads();
  if (t < 2) {
    signed char* dst = t == 0 ? Qs8 : Ks8;
#pragma unroll
    for (int it = 0; it < 4; ++it) {
      int c = tid + it * 256;            // 1024 chunks of 16B
      int rowL = c >> 3, cch = c & 7;
      int gr = i0 + rowL;
      int b = gr / N, nn = gr - b * N;
      int rem = rem0 + cch * 16;
      int h = rem >> 6, d = rem & 63;
      *(uint4a*)&dst[((size_t)(b * H + h) * N + nn) * 64 + d] =
          *(const uint4a*)&tile8[rowL * TLD8 + cch * 16];
    }
  } else {
#pragma unroll
    for (int it = 0; it < 4; ++it) {
      int c = tid + it * 256;
      int colL = c >> 3, tch = c & 7;
      int rem = rem0 + colL;
      int h = rem >> 6, d = rem & 63;
      int gr0 = i0 + tch * 16;
      int b0 = gr0 / N, nn0 = gr0 - b0 * N;
      if (nn0 + 16 <= N) {
        *(uint4a*)&Vt8[((size_t)(b0 * H + h) * 64 + d) * VNP + nn0] =
            *(const uint4a*)&tile8[colL * TLD8 + tch * 16];
      } else {
#pragma unroll
        for (int j = 0; j < 16; ++j) {
          int gr = gr0 + j;
          int b = gr / N, nn = gr - b * N;
          Vt8[((size_t)(b * H + h) * 64 + d) * VNP + nn] = tile8[colL * TLD8 + tch * 16 + j];
        }
      }
    }
  }
}

// ---------- fused attention v6: all-i8, 4 waves/block, XCD-affine ----------
__global__ __launch_bounds__(256) void attn_kernel(
    const signed char* __restrict__ Qs8, const signed char* __restrict__ Ks8,
    const signed char* __restrict__ Vt8, const double* __restrict__ tab,
    const float* __restrict__ movatt,
    const float* ca1p, const float* ca2p, const float* ca3p, const float* cipp,
    signed char* __restrict__ Os) {
  __shared__ double Tl1[9];    // exp((16i-128)*delta)
  __shared__ double Tl2[16];   // exp(j*delta)
  __shared__ signed char Al8[4][16 * AL8];
  int i = blockIdx.x;
  int xcd = i & 7;
  int q = i >> 3;
  int rt = q % 13;
  int grp = q / 13;
  int tid = threadIdx.x;
  int w = tid >> 6, lane = tid & 63;
  int bh = (grp * 4 + w) * 8 + xcd;
  int b = bh / H, h = bh - b * H;
  int g = lane >> 4, q16 = lane & 15;
  if (tid < 9) Tl1[tid] = tab[16 * tid];
  if (tid >= 32 && tid < 48) Tl2[tid - 32] = tab[129 + (tid - 32)];
  for (int ii = lane; ii < 192; ii += 64) {
    int row = ii / 12, cd = ii - row * 12;
    *(int*)&Al8[w][row * AL8 + 208 + cd * 4] = 0;
  }
  __syncthreads();
  double ca1 = (double)ca1p[0], ca2 = (double)ca2p[0], ca3 = (double)ca3p[0];
  double t1 = 0.5 * ca1, t2 = 0.5 * ca2, t3 = 0.5 * ca3;
  int q1 = (int)rint(4.0 * ca1), q2 = (int)rint(4.0 * ca2), q3 = (int)rint(4.0 * ca3);
  float cip = cipp[0];
  signed char cp = cip > 0.0f ? 1 : (cip < 0.0f ? -1 : 0);

  int4v qf = {};
  int qrow = rt * 16 + q16;
  if (qrow < N) qf = *(const int4v*)&Qs8[((size_t)bh * N + qrow) * 64 + g * 16];
  int4v sacc[13] = {};
#pragma unroll
  for (int ct = 0; ct < 13; ++ct) {
    int krow = ct * 16 + q16;
    int4v kf = {};
    if (krow < N) kf = *(const int4v*)&Ks8[((size_t)bh * N + krow) * 64 + g * 16];
    sacc[ct] = __builtin_amdgcn_mfma_i32_16x16x64_i8(qf, kf, sacc[ct], 0, 0, 0);
  }
#pragma unroll
  for (int r = 0; r < 4; ++r) {
    int rowg = rt * 16 + g * 4 + r;
    int rowc = rowg < N ? rowg : N - 1;
    const float* mrow = movatt + ((size_t)h * N + rowc) * N;
    int mx = -1000000;
#pragma unroll
    for (int ct = 0; ct < 13; ++ct) {
      int colc = ct * 16 + q16;
      if (colc < N) mx = max(mx, sacc[ct][r]);
    }
    mx = max(mx, __shfl_xor(mx, 1));
    mx = max(mx, __shfl_xor(mx, 2));
    mx = max(mx, __shfl_xor(mx, 4));
    mx = max(mx, __shfl_xor(mx, 8));
    double ev[13];
    double ssum = 0.0;
#pragma unroll
    for (int ct = 0; ct < 13; ++ct) {
      int colc = ct * 16 + q16;
      int idx = sacc[ct][r] - mx + 128;
      idx = idx > 128 ? 128 : idx;
      double e = (colc < N) ? Tl1[idx >> 4] * Tl2[idx & 15] : 0.0;
      ev[ct] = e;
      ssum += e;
    }
    ssum += __shfl_xor(ssum, 1);
    ssum += __shfl_xor(ssum, 2);
    ssum += __shfl_xor(ssum, 4);
    ssum += __shfl_xor(ssum, 8);
    double rec = 1.0 / ssum;
#pragma unroll
    for (int ct = 0; ct < 13; ++ct) {
      int colc = ct * 16 + q16;
      int colb = colc < N ? colc : N - 1;
      double at = ev[ct] * rec + (double)mrow[colb];
      int p4 = 0;
      double rr = at;
      if (rr > t1) { p4 += q1; rr -= ca1; }
      if (rr > t2) { p4 += q2; rr -= ca2; }
      if (rr > t3) { p4 += q3; }
      Al8[w][(g * 4 + r) * AL8 + colc] = (signed char)((colc < N) ? p4 : 0);
    }
  }
  int4v oacc[4] = {};
#pragma unroll
  for (int kt = 0; kt < 4; ++kt) {
    int4v af = *(const int4v*)&Al8[w][q16 * AL8 + kt * 64 + g * 16];
#pragma unroll
    for (int dt = 0; dt < 4; ++dt) {
      int4v bv = *(const int4v*)&Vt8[((size_t)bh * 64 + dt * 16 + q16) * VNP + kt * 64 + g * 16];
      oacc[dt] = __builtin_amdgcn_mfma_i32_16x16x64_i8(af, bv, oacc[dt], 0, 0, 0);
    }
  }
#pragma unroll
  for (int dt = 0; dt < 4; ++dt)
#pragma unroll
    for (int r = 0; r < 4; ++r) {
      int rowg = rt * 16 + g * 4 + r;
      if (rowg < N) {
        int d = dt * 16 + q16;
        int s = oacc[dt][r];
        Os[((size_t)(b * N + rowg)) * C + h * D + d] =
            s > 0 ? cp : (s < 0 ? (signed char)(-cp) : (signed char)0);
      }
    }
}

// ---------- GEMM2 ----------
__global__ __launch_bounds__(256) void gemm2_kernel(
    const signed char* __restrict__ Os, const signed char* __restrict__ Wps,
    const double* __restrict__ means, const float* cip, const float* __restrict__ proj_b,
    float* __restrict__ out) {
  int bx, by;
  if (!xcd_decode(blockIdx.x, C / 128, bx, by)) return;
  __shared__ __align__(16) char smem[32768];
  int4v acc[4][4] = {};
  int i0 = bx * 128, o0 = by * 128;
  gemm_dbuf_i8(Os, Wps, i0, o0, smem, acc);
  int lane = threadIdx.x & 63, w = threadIdx.x >> 6, wr = w >> 1, wc = w & 1;
  double cw_ = (double)cip[0] * means[1];
#pragma unroll
  for (int m = 0; m < 4; ++m)
#pragma unroll
    for (int n2 = 0; n2 < 4; ++n2)
#pragma unroll
      for (int r = 0; r < 4; ++r) {
        int row = i0 + wr * 64 + m * 16 + (lane >> 4) * 4 + r;
        int col = o0 + wc * 64 + n2 * 16 + (lane & 15);
        double v = (double)acc[m][n2][r] * cw_ + (double)proj_b[col];
        out[(size_t)row * C + col] = (float)v;
      }
}

extern "C" void kernel_launch(void* const* d_in, const int* in_sizes, int n_in,
                              void* d_out, int out_size, void* d_ws, size_t ws_size,
                              hipStream_t stream) {
  const float* x      = (const float*)d_in[0];
  const float* qkv_w  = (const float*)d_in[1];
  const float* proj_w = (const float*)d_in[2];
  const float* proj_b = (const float*)d_in[3];
  const float* movq   = (const float*)d_in[4];
  const float* movk   = (const float*)d_in[5];
  const float* movv   = (const float*)d_in[6];
  const float* movatt = (const float*)d_in[7];
  const float* c_inq  = (const float*)d_in[8];
  const float* c_q    = (const float*)d_in[9];
  const float* c_k    = (const float*)d_in[10];
  const float* c_v1   = (const float*)d_in[11];
  const float* c_v2   = (const float*)d_in[12];
  const float* c_v3   = (const float*)d_in[13];
  const float* c_a1   = (const float*)d_in[14];
  const float* c_a2   = (const float*)d_in[15];
  const float* c_a3   = (const float*)d_in[16];
  const float* c_inp  = (const float*)d_in[17];

  char* ws = (char*)d_ws;
  double* means = (double*)(ws + OFF_MEANS);
  double* tab   = (double*)(ws + OFF_TAB);
  double* partA = (double*)(ws + OFF_PARTA);
  double* partP = (double*)(ws + OFF_PARTP);
  signed char* Xs  = (signed char*)(ws + OFF_XS);
  signed char* Wqs = (signed char*)(ws + OFF_WQS);
  signed char* Wps = (signed char*)(ws + OFF_WPS);
  signed char* Qs8 = (signed char*)(ws + OFF_Q);
  signed char* Ks8 = (signed char*)(ws + OFF_K);
  signed char* Vt8 = (signed char*)(ws + OFF_VT);
  signed char* Os  = (signed char*)(ws + OFF_OS);

  reduce_abs2_kernel<<<512, 256, 0, stream>>>(qkv_w, O3C * C, proj_w, C * C, partA, partP);
  finalize_kernel<<<1, 256, 0, stream>>>(partA, partP, means, tab, c_q, c_k);
  sign8_all_kernel<<<2048, 256, 0, stream>>>(x, Xs, qkv_w, Wqs, proj_w, Wps,
                                             M * C / 8, O3C * C / 8, C * C / 8, c_inq);
  gemm1_kernel<<<104 * (O3C / 128), 256, 0, stream>>>(
      Xs, Wqs, means, c_inq, c_q, c_k, c_v1, c_v2, c_v3, movq, movk, movv, Qs8, Ks8, Vt8);
  attn_kernel<<<8 * 13 * (BH / 32), 256, 0, stream>>>(Qs8, Ks8, Vt8, tab, movatt, c_a1, c_a2, c_a3, c_inp, Os);
  gemm2_kernel<<<104 * (C / 128), 256, 0, stream>>>(
      Os, Wps, means, c_inp, proj_b, (float*)d_out);
}

// Round 16
// 160.480 us; speedup vs baseline: 1.7076x; 1.0054x over previous
//
#include <hip/hip_runtime.h>
#include <hip/hip_bf16.h>

typedef __attribute__((ext_vector_type(8))) short short8;
typedef __attribute__((ext_vector_type(4))) float f32x4;
typedef __attribute__((ext_vector_type(4))) int int4v;
typedef __attribute__((ext_vector_type(8))) char char8v;
typedef __attribute__((ext_vector_type(4), aligned(4))) unsigned int uint4a;

static constexpr int B = 64, N = 198, C = 768, H = 12, D = 64;
static constexpr int M = B * N;          // 12672 = 99*128
static constexpr int BH = B * H;         // 768
static constexpr int O3C = 3 * C;        // 2304 = 18*128
static constexpr int NXB = 99;           // M/128
static constexpr int TLD8 = 144;         // gemm1 epilogue i8 tile stride
static constexpr int AL8 = 272;          // attn P-stripe i8 stride
static constexpr int VNP = 256;          // V^T i8 padded cols

// ---- workspace layout (bytes) ----
static constexpr size_t OFF_MEANS = 0;
static constexpr size_t OFF_TAB   = 256;   // 129 + 16 doubles
static constexpr size_t OFF_PARTA = 2048;
static constexpr size_t OFF_PARTP = 4096;
static constexpr size_t OFF_XS    = 8192;
static constexpr size_t SZ_XS     = (size_t)M * C;           // sign(x) i8
static constexpr size_t OFF_WQS   = OFF_XS + SZ_XS;
static constexpr size_t SZ_WQS    = (size_t)O3C * C;
static constexpr size_t OFF_WPS   = OFF_WQS + SZ_WQS;
static constexpr size_t SZ_WPS    = (size_t)C * C;
static constexpr size_t OFF_Q     = OFF_WPS + SZ_WPS;
static constexpr size_t SZ_QK8    = (size_t)BH * N * D;      // i8
static constexpr size_t OFF_K     = OFF_Q + SZ_QK8;
static constexpr size_t OFF_VT    = OFF_K + SZ_QK8;
static constexpr size_t SZ_VT8    = (size_t)BH * D * VNP;    // i8
static constexpr size_t OFF_OS    = OFF_VT + SZ_VT8;         // i8 [M,C]

#define GLOAD_LDS16(g, l)                                                  \
  __builtin_amdgcn_global_load_lds(                                        \
      (const __attribute__((address_space(1))) void*)(g),                  \
      (__attribute__((address_space(3))) void*)(l), 16, 0, 0)

// ---------- merged mean(|W|) reduction: blocks 0..255 qkv_w, 256..511 proj_w ----------
__global__ void reduce_abs2_kernel(const float* __restrict__ qw, int nq,
                                   const float* __restrict__ pw, int np,
                                   double* __restrict__ partA, double* __restrict__ partP) {
  __shared__ double sm[256];
  const float* src;
  int n, b;
  double* dst;
  if (blockIdx.x < 256) { src = qw; n = nq; dst = partA; b = blockIdx.x; }
  else                  { src = pw; n = np; dst = partP; b = blockIdx.x - 256; }
  double s = 0.0;
  for (int i = b * 256 + threadIdx.x; i < n; i += 256 * 256)
    s += (double)fabsf(src[i]);
  sm[threadIdx.x] = s;
  __syncthreads();
  for (int off = 128; off > 0; off >>= 1) {
    if (threadIdx.x < (unsigned)off) sm[threadIdx.x] += sm[threadIdx.x + off];
    __syncthreads();
  }
  if (threadIdx.x == 0) dst[b] = sm[0];
}

__global__ void finalize_kernel(const double* __restrict__ pA, const double* __restrict__ pP,
                                double* __restrict__ means, double* __restrict__ tab,
                                const float* cq, const float* ck) {
  __shared__ double sm[256];
  int t = threadIdx.x;
  sm[t] = pA[t];
  __syncthreads();
  for (int off = 128; off > 0; off >>= 1) { if (t < off) sm[t] += sm[t + off]; __syncthreads(); }
  if (t == 0) means[0] = sm[0] / (double)((size_t)O3C * C);
  __syncthreads();
  sm[t] = pP[t];
  __syncthreads();
  for (int off = 128; off > 0; off >>= 1) { if (t < off) sm[t] += sm[t + off]; __syncthreads(); }
  if (t == 0) means[1] = sm[0] / (double)((size_t)C * C);
  double delta = (double)cq[0] * (double)ck[0] * 0.125;
  if (t < 129) tab[t] = exp((double)(t - 128) * delta);
  if (t < 16) tab[129 + t] = exp((double)t * delta);   // T2: exp(+j*delta)
}

// ---------- merged sign kernel: x | qkv_w | proj_w in one dispatch ----------
__global__ void sign8_all_kernel(const float* __restrict__ x, signed char* __restrict__ Xs,
                                 const float* __restrict__ qw, signed char* __restrict__ Wq,
                                 const float* __restrict__ pw, signed char* __restrict__ Wp,
                                 int nx8, int nq8, int np8, const float* alpha) {
  float a = alpha[0];
  signed char posx = (a > 0.0f) ? 1 : ((a < 0.0f) ? -1 : 0);
  int total = nx8 + nq8 + np8;
  int stride = 256 * gridDim.x;
  for (int i = blockIdx.x * 256 + threadIdx.x; i < total; i += stride) {
    const float* src;
    signed char* dst;
    int j;
    signed char pos;
    if (i < nx8) { src = x; dst = Xs; j = i; pos = posx; }
    else if (i < nx8 + nq8) { src = qw; dst = Wq; j = i - nx8; pos = 1; }
    else { src = pw; dst = Wp; j = i - nx8 - nq8; pos = 1; }
    signed char neg = (signed char)(-pos);
    const float4* xp = (const float4*)(src + (size_t)j * 8);
    float4 u = xp[0], v = xp[1];
    float vals[8] = {u.x, u.y, u.z, u.w, v.x, v.y, v.z, v.w};
    char8v s;
#pragma unroll
    for (int k = 0; k < 8; ++k)
      s[k] = vals[k] > 0.0f ? pos : (vals[k] < 0.0f ? neg : (signed char)0);
    *(char8v*)(dst + (size_t)j * 8) = s;
  }
}

// XCD-affinity decode
static __device__ inline bool xcd_decode(int lin, int nyb, int& x, int& y) {
  int k = lin & 7;
  int q = lin >> 3;
  int xi = q / nyb;
  y = q - xi * nyb;
  x = xi * 8 + k;
  return x < NXB;
}

// ---------- staged i8 GEMM, BK=64, depth-2 prefetch (3 buffers, counted vmcnt) ----------
static __device__ inline void stage_i8(const signed char* __restrict__ A,
                                       const signed char* __restrict__ Bmat,
                                       int i0, int o0, int k0,
                                       char* AsB, char* BsB) {
  int tid = threadIdx.x;
  int lane = tid & 63, w = tid >> 6;
#pragma unroll
  for (int c = 0; c < 2; ++c) {
    int ccb = w * 64 + c * 256;          // wave-uniform 16B-chunk base
    int cc = ccb + lane;
    int row = cc >> 2, cwl = cc & 3;
    int sc16 = (cwl ^ ((row >> 1) & 3)) * 16;   // pre-swizzled source
    GLOAD_LDS16(&A[(size_t)(i0 + row) * C + k0 + sc16], AsB + (size_t)ccb * 16);
    GLOAD_LDS16(&Bmat[(size_t)(o0 + row) * C + k0 + sc16], BsB + (size_t)ccb * 16);
  }
}

static __device__ inline void compute_i8(const signed char (*As)[64],
                                         const signed char (*Bs)[64],
                                         int4v acc[4][4]) {
  int lane = threadIdx.x & 63, w = threadIdx.x >> 6, wr = w >> 1, wc = w & 1;
  int g = lane >> 4;                     // k-chunk 0..3
  int4v af[4], bf[4];
#pragma unroll
  for (int m = 0; m < 4; ++m) {
    int row = wr * 64 + m * 16 + (lane & 15);
    af[m] = *(const int4v*)&As[row][((g ^ ((row >> 1) & 3))) * 16];
  }
#pragma unroll
  for (int n2 = 0; n2 < 4; ++n2) {
    int row = wc * 64 + n2 * 16 + (lane & 15);
    bf[n2] = *(const int4v*)&Bs[row][((g ^ ((row >> 1) & 3))) * 16];
  }
  __builtin_amdgcn_s_setprio(1);
#pragma unroll
  for (int m = 0; m < 4; ++m)
#pragma unroll
    for (int n2 = 0; n2 < 4; ++n2)
      acc[m][n2] = __builtin_amdgcn_mfma_i32_16x16x64_i8(af[m], bf[n2], acc[m][n2], 0, 0, 0);
  __builtin_amdgcn_s_setprio(0);
}

// Depth-2 pipeline over 3 buffers (smem + j*16384, j=0..2; A@0, B@8K in each).
// stage(t+2) issued at step t; vmcnt(4) at step end ensures stage(t+1) done
// while stage(t+2)'s 4 loads stay in flight ACROSS the barrier (T4 counted).
// RAW: buf[t%3] ready via prior step's vmcnt. WAR: stage(t+2) overwrites
// buf[(t-1)%3], whose readers finished before the barrier ending step t-1.
static __device__ inline void gemm_dbuf_i8(const signed char* __restrict__ A,
                                           const signed char* __restrict__ Bmat,
                                           int i0, int o0, char* smem, int4v acc[4][4]) {
  stage_i8(A, Bmat, i0, o0, 0, smem, smem + 8192);
  stage_i8(A, Bmat, i0, o0, 64, smem + 16384, smem + 16384 + 8192);
  asm volatile("s_waitcnt vmcnt(4)" ::: "memory");   // tile0 done; tile1 in flight
  __builtin_amdgcn_sched_barrier(0);
  __builtin_amdgcn_s_barrier();
#pragma unroll
  for (int t = 0; t < 12; ++t) {
    const int cu = t % 3;                 // compile-time under full unroll
    if (t < 10)
      stage_i8(A, Bmat, i0, o0, (t + 2) * 64,
               smem + ((t + 2) % 3) * 16384, smem + ((t + 2) % 3) * 16384 + 8192);
    compute_i8((const signed char(*)[64])(smem + cu * 16384),
               (const signed char(*)[64])(smem + cu * 16384 + 8192), acc);
    if (t < 10) {
      asm volatile("s_waitcnt vmcnt(4)" ::: "memory");   // tile t+1 done; t+2 in flight
      __builtin_amdgcn_sched_barrier(0);
      __builtin_amdgcn_s_barrier();
    } else if (t == 10) {
      asm volatile("s_waitcnt vmcnt(0)" ::: "memory");   // drain tile 11
      __builtin_amdgcn_sched_barrier(0);
      __builtin_amdgcn_s_barrier();
    }
  }
}

// ---------- GEMM1: qkv = sign(x) @ sign(Wqkv)^T, i8 outputs ----------
__global__ __launch_bounds__(256) void gemm1_kernel(
    const signed char* __restrict__ Xs, const signed char* __restrict__ Wqs,
    const double* __restrict__ means,
    const float* cin, const float* cq, const float* ck,
    const float* cv1, const float* cv2, const float* cv3,
    const float* __restrict__ movq, const float* __restrict__ movk, const float* __restrict__ movv,
    signed char* __restrict__ Qs8, signed char* __restrict__ Ks8, signed char* __restrict__ Vt8) {
  int bx, by;
  if (!xcd_decode(blockIdx.x, O3C / 128, bx, by)) return;
  __shared__ __align__(16) char smem[49152];
  signed char* tile8 = (signed char*)smem;   // [128][TLD8] = 18432 B, aliases staging
  int4v acc[4][4] = {};
  int i0 = bx * 128, o0 = by * 128;
  gemm_dbuf_i8(Xs, Wqs, i0, o0, smem, acc);
  int tid = threadIdx.x;
  int lane = tid & 63, w = tid >> 6, wr = w >> 1, wc = w & 1;
  double cw_ = (double)cin[0] * means[0];
  float dq = cq[0], dk = ck[0];
  signed char sq8 = dq > 0.0f ? 1 : (dq < 0.0f ? -1 : 0);
  signed char sk8 = dk > 0.0f ? 1 : (dk < 0.0f ? -1 : 0);
  double aa1 = fabs((double)cv1[0]), aa2 = fabs((double)cv2[0]), aa3 = fabs((double)cv3[0]);
  int t = o0 / C;
  int rem0 = o0 - t * C;
  signed char sg8 = t == 0 ? sq8 : sk8;
  const float* mov = t == 0 ? movq : (t == 1 ? movk : movv);
  __syncthreads();                        // staging reads done before tile8 overwrite
#pragma unroll
  for (int m = 0; m < 4; ++m)
#pragma unroll
    for (int n2 = 0; n2 < 4; ++n2)
#pragma unroll
      for (int r = 0; r < 4; ++r) {
        int rowL = wr * 64 + m * 16 + (lane >> 4) * 4 + r;
        int colL = wc * 64 + n2 * 16 + (lane & 15);
        int rem = rem0 + colL;
        int h = rem >> 6, d = rem & 63;
        double g = (double)acc[m][n2][r] * cw_;
        if (t < 2) {
          double v = g + (double)mov[h * D + d];
          tile8[rowL * TLD8 + colL] = v > 0.0 ? sg8 : (v < 0.0 ? (signed char)(-sg8) : (signed char)0);
        } else {
          double rr = g + (double)mov[h * D + d];
          double b1 = rr > 0.0 ? aa1 : (rr < 0.0 ? -aa1 : 0.0);
          rr -= b1;
          double b2 = rr > 0.0 ? aa2 : (rr < 0.0 ? -aa2 : 0.0);
          rr -= b2;
          double b3 = rr > 0.0 ? aa3 : (rr < 0.0 ? -aa3 : 0.0);
          tile8[colL * TLD8 + rowL] = (signed char)(int)rint(4.0 * (b1 + b2 + b3)); // transposed
        }
      }
  __syncthreads();
  if (t < 2) {
    signed char* dst = t == 0 ? Qs8 : Ks8;
#pragma unroll
    for (int it = 0; it < 4; ++it) {
      int c = tid + it * 256;            // 1024 chunks of 16B
      int rowL = c >> 3, cch = c & 7;
      int gr = i0 + rowL;
      int b = gr / N, nn = gr - b * N;
      int rem = rem0 + cch * 16;
      int h = rem >> 6, d = rem & 63;
      *(uint4a*)&dst[((size_t)(b * H + h) * N + nn) * 64 + d] =
          *(const uint4a*)&tile8[rowL * TLD8 + cch * 16];
    }
  } else {
#pragma unroll
    for (int it = 0; it < 4; ++it) {
      int c = tid + it * 256;
      int colL = c >> 3, tch = c & 7;
      int rem = rem0 + colL;
      int h = rem >> 6, d = rem & 63;
      int gr0 = i0 + tch * 16;
      int b0 = gr0 / N, nn0 = gr0 - b0 * N;
      if (nn0 + 16 <= N) {
        *(uint4a*)&Vt8[((size_t)(b0 * H + h) * 64 + d) * VNP + nn0] =
            *(const uint4a*)&tile8[colL * TLD8 + tch * 16];
      } else {
#pragma unroll
        for (int j = 0; j < 16; ++j) {
          int gr = gr0 + j;
          int b = gr / N, nn = gr - b * N;
          Vt8[((size_t)(b * H + h) * 64 + d) * VNP + nn] = tile8[colL * TLD8 + tch * 16 + j];
        }
      }
    }
  }
}

// ---------- fused attention v6: all-i8, 4 waves/block, XCD-affine ----------
__global__ __launch_bounds__(256) void attn_kernel(
    const signed char* __restrict__ Qs8, const signed char* __restrict__ Ks8,
    const signed char* __restrict__ Vt8, const double* __restrict__ tab,
    const float* __restrict__ movatt,
    const float* ca1p, const float* ca2p, const float* ca3p, const float* cipp,
    signed char* __restrict__ Os) {
  __shared__ double Tl1[9];    // exp((16i-128)*delta)
  __shared__ double Tl2[16];   // exp(j*delta)
  __shared__ signed char Al8[4][16 * AL8];
  int i = blockIdx.x;
  int xcd = i & 7;
  int q = i >> 3;
  int rt = q % 13;
  int grp = q / 13;
  int tid = threadIdx.x;
  int w = tid >> 6, lane = tid & 63;
  int bh = (grp * 4 + w) * 8 + xcd;
  int b = bh / H, h = bh - b * H;
  int g = lane >> 4, q16 = lane & 15;
  if (tid < 9) Tl1[tid] = tab[16 * tid];
  if (tid >= 32 && tid < 48) Tl2[tid - 32] = tab[129 + (tid - 32)];
  for (int ii = lane; ii < 192; ii += 64) {
    int row = ii / 12, cd = ii - row * 12;
    *(int*)&Al8[w][row * AL8 + 208 + cd * 4] = 0;
  }
  __syncthreads();
  double ca1 = (double)ca1p[0], ca2 = (double)ca2p[0], ca3 = (double)ca3p[0];
  double t1 = 0.5 * ca1, t2 = 0.5 * ca2, t3 = 0.5 * ca3;
  int q1 = (int)rint(4.0 * ca1), q2 = (int)rint(4.0 * ca2), q3 = (int)rint(4.0 * ca3);
  float cip = cipp[0];
  signed char cp = cip > 0.0f ? 1 : (cip < 0.0f ? -1 : 0);

  int4v qf = {};
  int qrow = rt * 16 + q16;
  if (qrow < N) qf = *(const int4v*)&Qs8[((size_t)bh * N + qrow) * 64 + g * 16];
  int4v sacc[13] = {};
#pragma unroll
  for (int ct = 0; ct < 13; ++ct) {
    int krow = ct * 16 + q16;
    int4v kf = {};
    if (krow < N) kf = *(const int4v*)&Ks8[((size_t)bh * N + krow) * 64 + g * 16];
    sacc[ct] = __builtin_amdgcn_mfma_i32_16x16x64_i8(qf, kf, sacc[ct], 0, 0, 0);
  }
#pragma unroll
  for (int r = 0; r < 4; ++r) {
    int rowg = rt * 16 + g * 4 + r;
    int rowc = rowg < N ? rowg : N - 1;
    const float* mrow = movatt + ((size_t)h * N + rowc) * N;
    int mx = -1000000;
#pragma unroll
    for (int ct = 0; ct < 13; ++ct) {
      int colc = ct * 16 + q16;
      if (colc < N) mx = max(mx, sacc[ct][r]);
    }
    mx = max(mx, __shfl_xor(mx, 1));
    mx = max(mx, __shfl_xor(mx, 2));
    mx = max(mx, __shfl_xor(mx, 4));
    mx = max(mx, __shfl_xor(mx, 8));
    double ev[13];
    double ssum = 0.0;
#pragma unroll
    for (int ct = 0; ct < 13; ++ct) {
      int colc = ct * 16 + q16;
      int idx = sacc[ct][r] - mx + 128;
      idx = idx > 128 ? 128 : idx;
      double e = (colc < N) ? Tl1[idx >> 4] * Tl2[idx & 15] : 0.0;
      ev[ct] = e;
      ssum += e;
    }
    ssum += __shfl_xor(ssum, 1);
    ssum += __shfl_xor(ssum, 2);
    ssum += __shfl_xor(ssum, 4);
    ssum += __shfl_xor(ssum, 8);
    double rec = 1.0 / ssum;
#pragma unroll
    for (int ct = 0; ct < 13; ++ct) {
      int colc = ct * 16 + q16;
      int colb = colc < N ? colc : N - 1;
      double at = ev[ct] * rec + (double)mrow[colb];
      int p4 = 0;
      double rr = at;
      if (rr > t1) { p4 += q1; rr -= ca1; }
      if (rr > t2) { p4 += q2; rr -= ca2; }
      if (rr > t3) { p4 += q3; }
      Al8[w][(g * 4 + r) * AL8 + colc] = (signed char)((colc < N) ? p4 : 0);
    }
  }
  int4v oacc[4] = {};
#pragma unroll
  for (int kt = 0; kt < 4; ++kt) {
    int4v af = *(const int4v*)&Al8[w][q16 * AL8 + kt * 64 + g * 16];
#pragma unroll
    for (int dt = 0; dt < 4; ++dt) {
      int4v bv = *(const int4v*)&Vt8[((size_t)bh * 64 + dt * 16 + q16) * VNP + kt * 64 + g * 16];
      oacc[dt] = __builtin_amdgcn_mfma_i32_16x16x64_i8(af, bv, oacc[dt], 0, 0, 0);
    }
  }
#pragma unroll
  for (int dt = 0; dt < 4; ++dt)
#pragma unroll
    for (int r = 0; r < 4; ++r) {
      int rowg = rt * 16 + g * 4 + r;
      if (rowg < N) {
        int d = dt * 16 + q16;
        int s = oacc[dt][r];
        Os[((size_t)(b * N + rowg)) * C + h * D + d] =
            s > 0 ? cp : (s < 0 ? (signed char)(-cp) : (signed char)0);
      }
    }
}

// ---------- GEMM2 ----------
__global__ __launch_bounds__(256) void gemm2_kernel(
    const signed char* __restrict__ Os, const signed char* __restrict__ Wps,
    const double* __restrict__ means, const float* cip, const float* __restrict__ proj_b,
    float* __restrict__ out) {
  int bx, by;
  if (!xcd_decode(blockIdx.x, C / 128, bx, by)) return;
  __shared__ __align__(16) char smem[49152];
  int4v acc[4][4] = {};
  int i0 = bx * 128, o0 = by * 128;
  gemm_dbuf_i8(Os, Wps, i0, o0, smem, acc);
  int lane = threadIdx.x & 63, w = threadIdx.x >> 6, wr = w >> 1, wc = w & 1;
  double cw_ = (double)cip[0] * means[1];
#pragma unroll
  for (int m = 0; m < 4; ++m)
#pragma unroll
    for (int n2 = 0; n2 < 4; ++n2)
#pragma unroll
      for (int r = 0; r < 4; ++r) {
        int row = i0 + wr * 64 + m * 16 + (lane >> 4) * 4 + r;
        int col = o0 + wc * 64 + n2 * 16 + (lane & 15);
        double v = (double)acc[m][n2][r] * cw_ + (double)proj_b[col];
        out[(size_t)row * C + col] = (float)v;
      }
}

extern "C" void kernel_launch(void* const* d_in, const int* in_sizes, int n_in,
                              void* d_out, int out_size, void* d_ws, size_t ws_size,
                              hipStream_t stream) {
  const float* x      = (const float*)d_in[0];
  const float* qkv_w  = (const float*)d_in[1];
  const float* proj_w = (const float*)d_in[2];
  const float* proj_b = (const float*)d_in[3];
  const float* movq   = (const float*)d_in[4];
  const float* movk   = (const float*)d_in[5];
  const float* movv   = (const float*)d_in[6];
  const float* movatt = (const float*)d_in[7];
  const float* c_inq  = (const float*)d_in[8];
  const float* c_q    = (const float*)d_in[9];
  const float* c_k    = (const float*)d_in[10];
  const float* c_v1   = (const float*)d_in[11];
  const float* c_v2   = (const float*)d_in[12];
  const float* c_v3   = (const float*)d_in[13];
  const float* c_a1   = (const float*)d_in[14];
  const float* c_a2   = (const float*)d_in[15];
  const float* c_a3   = (const float*)d_in[16];
  const float* c_inp  = (const float*)d_in[17];

  char* ws = (char*)d_ws;
  double* means = (double*)(ws + OFF_MEANS);
  double* tab   = (double*)(ws + OFF_TAB);
  double* partA = (double*)(ws + OFF_PARTA);
  double* partP = (double*)(ws + OFF_PARTP);
  signed char* Xs  = (signed char*)(ws + OFF_XS);
  signed char* Wqs = (signed char*)(ws + OFF_WQS);
  signed char* Wps = (signed char*)(ws + OFF_WPS);
  signed char* Qs8 = (signed char*)(ws + OFF_Q);
  signed char* Ks8 = (signed char*)(ws + OFF_K);
  signed char* Vt8 = (signed char*)(ws + OFF_VT);
  signed char* Os  = (signed char*)(ws + OFF_OS);

  reduce_abs2_kernel<<<512, 256, 0, stream>>>(qkv_w, O3C * C, proj_w, C * C, partA, partP);
  finalize_kernel<<<1, 256, 0, stream>>>(partA, partP, means, tab, c_q, c_k);
  sign8_all_kernel<<<2048, 256, 0, stream>>>(x, Xs, qkv_w, Wqs, proj_w, Wps,
                                             M * C / 8, O3C * C / 8, C * C / 8, c_inq);
  gemm1_kernel<<<104 * (O3C / 128), 256, 0, stream>>>(
      Xs, Wqs, means, c_inq, c_q, c_k, c_v1, c_v2, c_v3, movq, movk, movv, Qs8, Ks8, Vt8);
  attn_kernel<<<8 * 13 * (BH / 32), 256, 0, stream>>>(Qs8, Ks8, Vt8, tab, movatt, c_a1, c_a2, c_a3, c_inp, Os);
  gemm2_kernel<<<104 * (C / 128), 256, 0, stream>>>(
      Os, Wps, means, c_inp, proj_b, (float*)d_out);
}